// Round 12
// baseline (2086.480 us; speedup 1.0000x reference)
//
#include <hip/hip_runtime.h>
#include <math.h>

// Problem constants
#define Vv 8000
#define Ee 256
#define Hh 256
#define Tt 4
#define Bb 64
#define Ss 512

#define EPROJ_PER_DIR (Vv * 1024)   // 8,192,000 floats per direction
#define WMAT_PER_DIR  (Ee * 1024)   // 262,144 floats per direction

__device__ __forceinline__ float sigm(float x) { return 1.f / (1.f + expf(-x)); }

typedef _Float16 half2v __attribute__((ext_vector_type(2)));

__device__ __forceinline__ float fdot2u(unsigned int a, unsigned int b, float c) {
    half2v ha = __builtin_bit_cast(half2v, a);
    half2v hb = __builtin_bit_cast(half2v, b);
#if __has_builtin(__builtin_amdgcn_fdot2)
    return __builtin_amdgcn_fdot2(ha, hb, c, false);
#else
    return c + (float)ha[0] * (float)hb[0] + (float)ha[1] * (float)hb[1];
#endif
}

// ---------------------------------------------------------------------------
// prep: repack weights (identical to R11's proven layout).
//   WihP [dir][e][j']  j' = u*4+g <-> gate-row g*256+u    (GEMM B-matrix)
//   W16L [dir][us][i][tid][g] u32: LINEAR LDS image -- LSTM compute thread
//        tid = u_loc*8+kq2 reads LW4[i*512+tid] (conflict-free).
//        value.g = f16x2 of Whh[g*256 + us*64+u_loc][2kp..2kp+1], kp = kq2*16+i
//   bP   [dir][j']
//   WlinQ[dir][u][t] float4/u = Wlin[t][dir*256+u]        (emission)
// ---------------------------------------------------------------------------
__global__ void prep_kernel(const float* __restrict__ Wih_f, const float* __restrict__ Whh_f,
                            const float* __restrict__ b_f,
                            const float* __restrict__ Wih_b, const float* __restrict__ Whh_b,
                            const float* __restrict__ b_b,
                            const float* __restrict__ Wlin,
                            float* __restrict__ WihP, unsigned int* __restrict__ W16L,
                            float* __restrict__ bP, float* __restrict__ WlinQ)
{
    int tid = blockIdx.x * blockDim.x + threadIdx.x;   // [0, 2*262144)
    int dir = tid >> 18;
    int r   = tid & 262143;
    int k   = r >> 10;        // 0..255
    int jp  = r & 1023;       // j'
    int u   = jp >> 2;
    int g   = jp & 3;
    int row = g * 256 + u;    // original gate row
    const float* Wih = dir ? Wih_b : Wih_f;
    const float* Whh = dir ? Whh_b : Whh_f;
    const float* bv  = dir ? b_b   : b_f;
    WihP[dir * WMAT_PER_DIR + k * 1024 + jp] = Wih[row * 256 + k];
    if (!(k & 1)) {
        int kp = k >> 1;                 // 0..127
        int us = u >> 6, u_loc = u & 63;
        int kq2 = kp >> 4, i = kp & 15;
        union { _Float16 h[2]; unsigned int u32; } pk;
        pk.h[0] = (_Float16)Whh[row * 256 + k];
        pk.h[1] = (_Float16)Whh[row * 256 + k + 1];
        W16L[((dir * 4 + us) * 8192 + i * 512 + u_loc * 8 + kq2) * 4 + g] = pk.u32;
    }
    if (r < 1024) {
        bP[dir * 1024 + jp] = bv[row];
        int uu = r >> 2, tt = r & 3;
        WlinQ[(dir * 256 + uu) * 4 + tt] = Wlin[tt * (2 * Hh) + dir * 256 + uu];
    }
}

// ---------------------------------------------------------------------------
// embproj GEMM: embproj[dir][v][j'] = sum_e emb[v][e]*WihP[dir][e][j'] + bP[dir][j']
// ---------------------------------------------------------------------------
#define BM 64
#define BN 128
#define BK 16
__global__ __launch_bounds__(256) void embproj_gemm(const float* __restrict__ emb,
                                                    const float* __restrict__ WihP,
                                                    const float* __restrict__ bP,
                                                    float* __restrict__ embproj)
{
    int dir = blockIdx.z;
    const float* Bmat = WihP + dir * WMAT_PER_DIR;
    float* C = embproj + (size_t)dir * EPROJ_PER_DIR;
    int m0 = blockIdx.x * BM;
    int n0 = blockIdx.y * BN;

    __shared__ float As[BK][BM];
    __shared__ float Bs[BK][BN];

    int t = threadIdx.x;
    int tm = (t & 15) * 4;
    int tn = (t >> 4) * 8;
    float acc[4][8];
    #pragma unroll
    for (int i = 0; i < 4; ++i)
        #pragma unroll
        for (int j = 0; j < 8; ++j) acc[i][j] = 0.f;

    for (int k0 = 0; k0 < Ee; k0 += BK) {
        {   // A tile 64x16
            int row = t >> 2, seg = t & 3;
            float4 a4 = *(const float4*)(&emb[(size_t)(m0 + row) * Ee + k0 + seg * 4]);
            As[seg * 4 + 0][row] = a4.x;
            As[seg * 4 + 1][row] = a4.y;
            As[seg * 4 + 2][row] = a4.z;
            As[seg * 4 + 3][row] = a4.w;
        }
        {   // B tile 16x128
            int kk = t >> 4, nn = (t & 15) * 8;
            float4 b0 = *(const float4*)(&Bmat[(size_t)(k0 + kk) * 1024 + n0 + nn]);
            float4 b1 = *(const float4*)(&Bmat[(size_t)(k0 + kk) * 1024 + n0 + nn + 4]);
            *(float4*)&Bs[kk][nn]     = b0;
            *(float4*)&Bs[kk][nn + 4] = b1;
        }
        __syncthreads();
        #pragma unroll
        for (int k = 0; k < BK; ++k) {
            float4 a  = *(const float4*)&As[k][tm];
            float4 b0 = *(const float4*)&Bs[k][tn];
            float4 b1 = *(const float4*)&Bs[k][tn + 4];
            float av[4] = {a.x, a.y, a.z, a.w};
            float bv[8] = {b0.x, b0.y, b0.z, b0.w, b1.x, b1.y, b1.z, b1.w};
            #pragma unroll
            for (int i = 0; i < 4; ++i)
                #pragma unroll
                for (int j = 0; j < 8; ++j)
                    acc[i][j] += av[i] * bv[j];
        }
        __syncthreads();
    }
    #pragma unroll
    for (int i = 0; i < 4; ++i) {
        int m = m0 + tm + i;
        #pragma unroll
        for (int j = 0; j < 8; j += 4) {
            float4 o;
            o.x = acc[i][j + 0] + bP[dir * 1024 + n0 + tn + j + 0];
            o.y = acc[i][j + 1] + bP[dir * 1024 + n0 + tn + j + 1];
            o.z = acc[i][j + 2] + bP[dir * 1024 + n0 + tn + j + 2];
            o.w = acc[i][j + 3] + bP[dir * 1024 + n0 + tn + j + 3];
            *(float4*)&C[(size_t)m * 1024 + n0 + tn + j] = o;
        }
    }
}

// ---------------------------------------------------------------------------
// LSTM recurrence, R12: STAGGERED batch pipeline. Team = (dir, batch-pair),
// 4 WGs (us quarters). WG = 576 threads: waves 0-7 compute (512 thr, same
// layout as R11), wave 8 = dedicated comm wave. 3 phases/step:
//   P1: dot(A,s)  [+ wave8: import h_B(s-1) peers]        b1
//   P2: wave0 act(A,s)+publish;  waves0-7 dot(B,s)        b2
//   P3: wave1 act(B,s)+publish;  wave8: import h_A(s) peers   b3
// Each import overlaps a dot/act phase instead of stalling the team (R11
// exposed two L3 round trips per step; here ~one). Weights are loaded to
// registers in P1 and REUSED for dot(B) (keeps LDS weight traffic 128KB/step).
// Sync semantics unchanged from proven R11: relaxed agent atomics, producer
// s_waitcnt vmcnt(0) before flag, monotonic flags, parity double-buffered hg
// (2-step overwrite distance), bounded spin budgets.
// ---------------------------------------------------------------------------
__global__ __launch_bounds__(576) void lstm_stag_kernel(
    const int* __restrict__ sentence,
    const float* __restrict__ embproj,
    const unsigned int* __restrict__ W16L,
    const float* __restrict__ WlinQ,
    unsigned int* __restrict__ hg,
    int* __restrict__ flags,
    float* __restrict__ emisP)
{
    extern __shared__ char smem[];
    uint4*        LW4  = (uint4*)smem;                        // 128 KB weights (linear)
    unsigned int* h16  = (unsigned int*)(smem + 131072);      // [bat][8 slices][20] u32
    float*        part = (float*)(smem + 131072 + 1280);      // [bat][64][4] f32

    const int bx   = blockIdx.x;
    const int us   = bx >> 6;          // 0..3
    const int team = bx & 63;          // members bx = team + 64*q: same XCD mod 8
    const int dir  = team >> 5;
    const int bg   = team & 31;
    const int b0   = bg * 2;
    const int tid  = threadIdx.x;
    const int kq2   = tid & 7;         // 0..7 (32-k slice), compute threads
    const int wave  = tid >> 6;        // 0..8
    const int lane  = tid & 63;

    // ---- stage weights into LDS (linear, coalesced, conflict-free reads) ----
    if (tid < 512) {
        const uint4* Wsrc = (const uint4*)(W16L + ((size_t)(dir * 4 + us) << 15));
        #pragma unroll
        for (int i = 0; i < 16; ++i)
            LW4[i * 512 + tid] = Wsrc[i * 512 + tid];
    }
    if (tid < 320) h16[tid] = 0u;      // h(-1) = 0, both batches (incl pads)

    const float* EP = embproj + (size_t)dir * EPROJ_PER_DIR;
    const int fl_base = team * 8;
    unsigned int* hgT = hg + (size_t)team * 512;   // [par][bat][q*32+idx] u32

    // act-wave persistent state (waves 0/1; bat = wave)
    const int bat = (wave < 2) ? wave : 0;
    const int b = b0 + bat;
    const int* sent = sentence + (size_t)b * Ss;
    float c = 0.f;
    float4 wl = make_float4(0.f, 0.f, 0.f, 0.f);
    float4 ep = make_float4(0.f, 0.f, 0.f, 0.f);
    const int uact = us * 64 + lane;
    if (wave < 2) {
        wl = *(const float4*)&WlinQ[(dir * 256 + uact) * 4];
        const int pos0 = dir ? (Ss - 1) : 0;
        ep = *(const float4*)(EP + (size_t)sent[pos0] * 1024 + uact * 4);
    }
    const int di = us * 2 + dir;       // emission partial buffer index
    const int l8 = tid - 512;          // comm-wave lane (0..63), valid wave==8
    long budget = 30000000;            // bounded spin: wrong answer, not hang

    __syncthreads();

    for (int s = 0; s < Ss; ++s) {
        const int wr = s & 1;
        const int pos = dir ? (Ss - 1 - s) : s;
        uint4 w_reg[16];

        // ================= P1: dot(A,s)  ||  wave8 import h_B(s-1) ==========
        if (tid < 512) {
            const int hb = 0 * 160 + kq2 * 20;       // batch A, swizzled slices
            unsigned int hA[16];
            #pragma unroll
            for (int r = 0; r < 4; ++r) {
                uint4 qa = *(const uint4*)&h16[hb + r * 4];
                hA[r*4] = qa.x; hA[r*4+1] = qa.y; hA[r*4+2] = qa.z; hA[r*4+3] = qa.w;
            }
            float4 aA = make_float4(0.f, 0.f, 0.f, 0.f);
            #pragma unroll
            for (int i = 0; i < 16; ++i) {
                w_reg[i] = LW4[i * 512 + tid];
                aA.x = fdot2u(hA[i], w_reg[i].x, aA.x);
                aA.y = fdot2u(hA[i], w_reg[i].y, aA.y);
                aA.z = fdot2u(hA[i], w_reg[i].z, aA.z);
                aA.w = fdot2u(hA[i], w_reg[i].w, aA.w);
            }
            #pragma unroll
            for (int off = 4; off > 0; off >>= 1) {
                aA.x += __shfl_down(aA.x, off); aA.y += __shfl_down(aA.y, off);
                aA.z += __shfl_down(aA.z, off); aA.w += __shfl_down(aA.w, off);
            }
            if (kq2 == 0)
                *(float4*)&part[(0 * 64 + (tid >> 3)) * 4] = aA;
        } else if (s > 0) {
            // import h_B(s-1): poll 3 peer flags (value >= s), one data pass
            const int ipar = (s - 1) & 1;
            if (l8 < 3) {
                const int q = l8 + (l8 >= us);
                const int* fp = &flags[fl_base + q * 2 + 1];
                while (__hip_atomic_load(fp, __ATOMIC_RELAXED,
                                         __HIP_MEMORY_SCOPE_AGENT) < s) {
                    __builtin_amdgcn_s_sleep(1);
                    if (--budget < 0) break;
                }
            }
            asm volatile("" ::: "memory");   // keep data loads below the poll
            const int idx0 = l8 * 2;                 // u32 idx in [bat] block
            const unsigned int* src = &hgT[(ipar * 2 + 1) * 128 + idx0];
            unsigned int v0 = __hip_atomic_load(src + 0, __ATOMIC_RELAXED,
                                                __HIP_MEMORY_SCOPE_AGENT);
            unsigned int v1 = __hip_atomic_load(src + 1, __ATOMIC_RELAXED,
                                                __HIP_MEMORY_SCOPE_AGENT);
            if ((idx0 >> 5) != us) {                 // skip own quarter
                h16[1 * 160 + ((idx0)     >> 4) * 20 + ((idx0)     & 15)] = v0;
                h16[1 * 160 + ((idx0 + 1) >> 4) * 20 + ((idx0 + 1) & 15)] = v1;
            }
        }
        __syncthreads();   // b1: part[A] ready; h16[B] = h_B(s-1) complete

        // ================= P2: wave0 act(A)+publish;  dot(B,s) ==============
        if (wave == 0) {
            const float4 pp = *(const float4*)&part[(0 * 64 + lane) * 4];
            const float gi = pp.x + ep.x, gf = pp.y + ep.y,
                        gg = pp.z + ep.z, go = pp.w + ep.w;
            c = sigm(gf) * c + sigm(gi) * tanhf(gg);
            const float h = sigm(go) * tanhf(c);
            const float hn = __shfl_down(h, 1);
            if (!(lane & 1)) {
                union { _Float16 hh[2]; unsigned int u32; } pk;
                pk.hh[0] = (_Float16)h; pk.hh[1] = (_Float16)hn;
                const int kp = us * 32 + (lane >> 1);
                h16[0 * 160 + (kp >> 4) * 20 + (kp & 15)] = pk.u32;
                __hip_atomic_store(&hgT[(wr * 2 + 0) * 128 + kp],
                                   pk.u32, __ATOMIC_RELAXED, __HIP_MEMORY_SCOPE_AGENT);
            }
            asm volatile("s_waitcnt vmcnt(0)" ::: "memory");   // h stores done
            if (lane == 0)
                __hip_atomic_store(&flags[fl_base + us * 2 + 0], s + 1,
                                   __ATOMIC_RELAXED, __HIP_MEMORY_SCOPE_AGENT);
            float4 em = make_float4(h * wl.x, h * wl.y, h * wl.z, h * wl.w);
            #pragma unroll
            for (int off = 32; off > 0; off >>= 1) {
                em.x += __shfl_down(em.x, off); em.y += __shfl_down(em.y, off);
                em.z += __shfl_down(em.z, off); em.w += __shfl_down(em.w, off);
            }
            if (lane == 0)
                *(float4*)&emisP[(((size_t)di * Ss + pos) * Bb + b) * 4] = em;
            if (s + 1 < Ss) {
                const int pn = dir ? (Ss - 2 - s) : (s + 1);
                ep = *(const float4*)(EP + (size_t)sent[pn] * 1024 + uact * 4);
            }
        }
        if (tid < 512) {   // dot(B,s): reuse w_reg, read h16[B]
            const int hb = 1 * 160 + kq2 * 20;
            unsigned int hB[16];
            #pragma unroll
            for (int r = 0; r < 4; ++r) {
                uint4 qb = *(const uint4*)&h16[hb + r * 4];
                hB[r*4] = qb.x; hB[r*4+1] = qb.y; hB[r*4+2] = qb.z; hB[r*4+3] = qb.w;
            }
            float4 aB = make_float4(0.f, 0.f, 0.f, 0.f);
            #pragma unroll
            for (int i = 0; i < 16; ++i) {
                aB.x = fdot2u(hB[i], w_reg[i].x, aB.x);
                aB.y = fdot2u(hB[i], w_reg[i].y, aB.y);
                aB.z = fdot2u(hB[i], w_reg[i].z, aB.z);
                aB.w = fdot2u(hB[i], w_reg[i].w, aB.w);
            }
            #pragma unroll
            for (int off = 4; off > 0; off >>= 1) {
                aB.x += __shfl_down(aB.x, off); aB.y += __shfl_down(aB.y, off);
                aB.z += __shfl_down(aB.z, off); aB.w += __shfl_down(aB.w, off);
            }
            if (kq2 == 0)
                *(float4*)&part[(1 * 64 + (tid >> 3)) * 4] = aB;
        }
        __syncthreads();   // b2: part[B] ready

        // ================= P3: wave1 act(B)+publish;  wave8 import h_A(s) ===
        if (wave == 1) {
            const float4 pp = *(const float4*)&part[(1 * 64 + lane) * 4];
            const float gi = pp.x + ep.x, gf = pp.y + ep.y,
                        gg = pp.z + ep.z, go = pp.w + ep.w;
            c = sigm(gf) * c + sigm(gi) * tanhf(gg);
            const float h = sigm(go) * tanhf(c);
            const float hn = __shfl_down(h, 1);
            if (!(lane & 1)) {
                union { _Float16 hh[2]; unsigned int u32; } pk;
                pk.hh[0] = (_Float16)h; pk.hh[1] = (_Float16)hn;
                const int kp = us * 32 + (lane >> 1);
                h16[1 * 160 + (kp >> 4) * 20 + (kp & 15)] = pk.u32;
                __hip_atomic_store(&hgT[(wr * 2 + 1) * 128 + kp],
                                   pk.u32, __ATOMIC_RELAXED, __HIP_MEMORY_SCOPE_AGENT);
            }
            asm volatile("s_waitcnt vmcnt(0)" ::: "memory");
            if (lane == 0)
                __hip_atomic_store(&flags[fl_base + us * 2 + 1], s + 1,
                                   __ATOMIC_RELAXED, __HIP_MEMORY_SCOPE_AGENT);
            float4 em = make_float4(h * wl.x, h * wl.y, h * wl.z, h * wl.w);
            #pragma unroll
            for (int off = 32; off > 0; off >>= 1) {
                em.x += __shfl_down(em.x, off); em.y += __shfl_down(em.y, off);
                em.z += __shfl_down(em.z, off); em.w += __shfl_down(em.w, off);
            }
            if (lane == 0)
                *(float4*)&emisP[(((size_t)di * Ss + pos) * Bb + b) * 4] = em;
            if (s + 1 < Ss) {
                const int pn = dir ? (Ss - 2 - s) : (s + 1);
                ep = *(const float4*)(EP + (size_t)sent[pn] * 1024 + uact * 4);
            }
        } else if (wave == 8 && s + 1 < Ss) {
            // import h_A(s): poll 3 peer flags (value >= s+1), one data pass
            if (l8 < 3) {
                const int q = l8 + (l8 >= us);
                const int* fp = &flags[fl_base + q * 2 + 0];
                while (__hip_atomic_load(fp, __ATOMIC_RELAXED,
                                         __HIP_MEMORY_SCOPE_AGENT) < s + 1) {
                    __builtin_amdgcn_s_sleep(1);
                    if (--budget < 0) break;
                }
            }
            asm volatile("" ::: "memory");
            const int idx0 = l8 * 2;
            const unsigned int* src = &hgT[(wr * 2 + 0) * 128 + idx0];
            unsigned int v0 = __hip_atomic_load(src + 0, __ATOMIC_RELAXED,
                                                __HIP_MEMORY_SCOPE_AGENT);
            unsigned int v1 = __hip_atomic_load(src + 1, __ATOMIC_RELAXED,
                                                __HIP_MEMORY_SCOPE_AGENT);
            if ((idx0 >> 5) != us) {
                h16[0 * 160 + ((idx0)     >> 4) * 20 + ((idx0)     & 15)] = v0;
                h16[0 * 160 + ((idx0 + 1) >> 4) * 20 + ((idx0 + 1) & 15)] = v1;
            }
        }
        __syncthreads();   // b3: h16[A] = h_A(s) complete
    }
}

// ---------------------------------------------------------------------------
// merge 8 emission partials -> emis[s][b][4]
// ---------------------------------------------------------------------------
__global__ __launch_bounds__(256) void emis_merge_kernel(const float* __restrict__ emisP,
                                                         float* __restrict__ emis)
{
    const int i = blockIdx.x * 256 + threadIdx.x;   // < 131072
    float v = 0.f;
    #pragma unroll
    for (int d = 0; d < 8; ++d) v += emisP[(size_t)d * (Ss * Bb * 4) + i];
    emis[i] = v;
}

// ---------------------------------------------------------------------------
// Fused CRF + Viterbi tail. grid 8 x 64 threads.
// ---------------------------------------------------------------------------
__global__ __launch_bounds__(64) void tail_kernel(
    const float* __restrict__ emis,
    const float* __restrict__ blin, const float* __restrict__ start_t,
    const float* __restrict__ end_t, const float* __restrict__ trans,
    const int* __restrict__ tags, float* __restrict__ out_tags,
    float* __restrict__ out_loss)
{
    const int blk = blockIdx.x;
    const int t = threadIdx.x;
    const int b_loc = t >> 2, j = t & 3;
    const int base = t & ~3;

    if (blk < 4) {
        __shared__ unsigned char bp_sh[16][513][4];
        __shared__ unsigned char tag_sh[16][520];
        const int b = blk * 16 + b_loc;
        const float trj0 = trans[0*4+j], trj1 = trans[1*4+j],
                    trj2 = trans[2*4+j], trj3 = trans[3*4+j];
        const float blj = blin[j];
        float score = start_t[j] + emis[(size_t)b*4 + j] + blj;
        for (int s = 1; s < Ss; ++s) {
            const float e = emis[((size_t)s*Bb + b)*4 + j] + blj;
            const float s0 = __shfl(score, base+0), s1 = __shfl(score, base+1),
                        s2 = __shfl(score, base+2), s3 = __shfl(score, base+3);
            float best = s0 + trj0; int bi = 0;
            float v = s1 + trj1; if (v > best) { best = v; bi = 1; }
            v = s2 + trj2; if (v > best) { best = v; bi = 2; }
            v = s3 + trj3; if (v > best) { best = v; bi = 3; }
            score = best + e;
            bp_sh[b_loc][s][j] = (unsigned char)bi;
        }
        const float fv = score + end_t[j];
        const float f0 = __shfl(fv, base+0), f1 = __shfl(fv, base+1),
                    f2 = __shfl(fv, base+2), f3 = __shfl(fv, base+3);
        __syncthreads();
        if (j == 0) {   // backtrack (first-occurrence argmax, like jnp)
            float best = f0; int tag = 0;
            if (f1 > best) { best = f1; tag = 1; }
            if (f2 > best) { best = f2; tag = 2; }
            if (f3 > best) { best = f3; tag = 3; }
            tag_sh[b_loc][Ss-1] = (unsigned char)tag;
            for (int s = Ss - 1; s >= 1; --s) {
                tag = bp_sh[b_loc][s][tag];
                tag_sh[b_loc][s-1] = (unsigned char)tag;
            }
        }
        __syncthreads();
        for (int idx = t; idx < 16 * Ss; idx += 64) {
            const int bl = idx >> 9, s = idx & (Ss - 1);
            out_tags[(size_t)(blk*16 + bl) * Ss + s] = (float)tag_sh[bl][s];
        }
    } else {
        const int b = (blk - 4) * 16 + b_loc;
        const float trj0 = trans[0*4+j], trj1 = trans[1*4+j],
                    trj2 = trans[2*4+j], trj3 = trans[3*4+j];
        const float blj = blin[j];
        float alpha = start_t[j] + emis[(size_t)b*4 + j] + blj;
        for (int s = 1; s < Ss; ++s) {
            const float e = emis[((size_t)s*Bb + b)*4 + j] + blj;
            const float a0 = __shfl(alpha, base+0), a1 = __shfl(alpha, base+1),
                        a2 = __shfl(alpha, base+2), a3 = __shfl(alpha, base+3);
            const float x0 = a0 + trj0, x1 = a1 + trj1, x2 = a2 + trj2, x3 = a3 + trj3;
            const float m = fmaxf(fmaxf(x0, x1), fmaxf(x2, x3));
            alpha = m + logf(expf(x0-m) + expf(x1-m) + expf(x2-m) + expf(x3-m)) + e;
        }
        const float dv = alpha + end_t[j];
        const float d0 = __shfl(dv, base+0), d1 = __shfl(dv, base+1),
                    d2 = __shfl(dv, base+2), d3 = __shfl(dv, base+3);
        const float dm = fmaxf(fmaxf(d0, d1), fmaxf(d2, d3));
        const float denom = dm + logf(expf(d0-dm) + expf(d1-dm) + expf(d2-dm) + expf(d3-dm));

        const int lo = j * 128, hi = lo + 128;
        float num = 0.f;
        int tprev = (lo > 0) ? tags[(size_t)b*Ss + lo - 1] : 0;
        if (j == 0) num += start_t[tags[(size_t)b*Ss]];
        if (j == 3) num += end_t[tags[(size_t)b*Ss + Ss - 1]];
        for (int s = lo; s < hi; ++s) {
            const int tg = tags[(size_t)b*Ss + s];
            num += emis[((size_t)s*Bb + b)*4 + tg] + blin[tg];
            if (s > 0) num += trans[tprev*4 + tg];
            tprev = tg;
        }
        num += __shfl_xor(num, 1);
        num += __shfl_xor(num, 2);
        float lb = (j == 0) ? (denom - num) : 0.f;
        #pragma unroll
        for (int off = 32; off > 0; off >>= 1) lb += __shfl_down(lb, off);
        if (t == 0) atomicAdd(out_loss, lb);
    }
}

// ---------------------------------------------------------------------------
extern "C" void kernel_launch(void* const* d_in, const int* in_sizes, int n_in,
                              void* d_out, int out_size, void* d_ws, size_t ws_size,
                              hipStream_t stream)
{
    const int*   sentence = (const int*)d_in[0];
    const int*   tags     = (const int*)d_in[1];
    const float* emb      = (const float*)d_in[3];
    const float* Wih_f    = (const float*)d_in[4];
    const float* Whh_f    = (const float*)d_in[5];
    const float* b_f      = (const float*)d_in[6];
    const float* Wih_b    = (const float*)d_in[7];
    const float* Whh_b    = (const float*)d_in[8];
    const float* b_b      = (const float*)d_in[9];
    const float* Wlin     = (const float*)d_in[10];
    const float* blin     = (const float*)d_in[11];
    const float* start_t  = (const float*)d_in[12];
    const float* end_t    = (const float*)d_in[13];
    const float* trans    = (const float*)d_in[14];

    // workspace layout (floats)
    float*        embproj = (float*)d_ws;                      // 16,384,000
    float*        WihP    = embproj + 2 * EPROJ_PER_DIR;       // 524,288 (reused)
    unsigned int* W16L    = (unsigned int*)(WihP + 2 * WMAT_PER_DIR);  // 262,144 u32
    float*        bP      = (float*)(W16L + 262144);           // 2048
    float*        WlinQ   = bP + 2048;                         // 2048
    float*        emisP   = WlinQ + 2048;                      // 8*512*64*4
    float*        emis    = emisP + 8 * Ss * Bb * 4;           // 131,072

    // WihP region dead after the GEMM -> flags + h exchange
    int*          flags  = (int*)WihP;                         // 512 ints
    unsigned int* hg     = (unsigned int*)(WihP + 1024);       // 64*512 u32

    prep_kernel<<<2048, 256, 0, stream>>>(Wih_f, Whh_f, b_f, Wih_b, Whh_b, b_b, Wlin,
                                          WihP, W16L, bP, WlinQ);
    dim3 gg(Vv / BM, 1024 / BN, 2);
    embproj_gemm<<<gg, 256, 0, stream>>>(emb, WihP, bP, embproj);

    // zero flags + gap + hg: a budget-expired poll reads h = 0 (finite-wrong,
    // diagnosable) instead of stale-float NaN f16.
    hipMemsetAsync(flags, 0, 33792 * sizeof(int), stream);

    const int* k_sent = sentence;
    const float* k_ep = embproj;
    const unsigned int* k_w = W16L;
    const float* k_wlin = WlinQ;
    unsigned int* k_hg = hg;
    int* k_fl = flags;
    float* k_em = emisP;
    void* args[] = { (void*)&k_sent, (void*)&k_ep, (void*)&k_w, (void*)&k_wlin,
                     (void*)&k_hg, (void*)&k_fl, (void*)&k_em };
    hipLaunchCooperativeKernel((const void*)lstm_stag_kernel, dim3(256), dim3(576),
                               args, 131072 + 1280 + 2048, stream);

    emis_merge_kernel<<<512, 256, 0, stream>>>(emisP, emis);

    float* out = (float*)d_out;
    float* out_loss = out + Bb * Ss;
    hipMemsetAsync(out_loss, 0, sizeof(float), stream);
    tail_kernel<<<8, 64, 0, stream>>>(emis, blin, start_t, end_t, trans,
                                      tags, out, out_loss);
}

// Round 13
// 1096.338 us; speedup vs baseline: 1.9031x; 1.9031x over previous
//
#include <hip/hip_runtime.h>
#include <math.h>

// Problem constants
#define Vv 8000
#define Ee 256
#define Hh 256
#define Tt 4
#define Bb 64
#define Ss 512

#define EPROJ_PER_DIR (Vv * 1024)   // 8,192,000 floats per direction
#define WMAT_PER_DIR  (Ee * 1024)   // 262,144 floats per direction

// int8 weight image geometry (per dir = 65536 u32 = 256KB):
//   64 k-words (kw) of 4 k each. static kw 0..35 (18 uint4-slots), streamed
//   kw 36..63 (14 uint4-slots). u32 at (sec, slot, t, j):
//     kw = (sec? 36:0) + 2*slot + (j>>1), rr = j&1
//     row_orig = ((t<256?0:2)+rr)*256 + (t&255)   [gate-major, as input Whh]
//   Thread t consumes uint4 (slot*512+t) -> lane-linear, coalesced/conflict-free.
#define NSTAT 18
#define NSTRM 14
#define STAT_U32 (NSTAT * 512 * 4)   // 36864

__device__ __forceinline__ float sigm(float x) { return 1.f / (1.f + expf(-x)); }

#if defined(__has_builtin)
# if __has_builtin(__builtin_amdgcn_sdot4)
#  define HAS_SDOT4 1
# endif
#endif

__device__ __forceinline__ int dot4i8(unsigned a, unsigned b, int c) {
#ifdef HAS_SDOT4
    return __builtin_amdgcn_sdot4((int)a, (int)b, c, false);
#else
    int s = c;
    #pragma unroll
    for (int i = 0; i < 4; ++i) {
        const int xa = ((int)(a << (24 - 8 * i))) >> 24;
        const int xb = ((int)(b << (24 - 8 * i))) >> 24;
        s += xa * xb;
    }
    return s;
#endif
}

// ---------------------------------------------------------------------------
// prep1: WihP (GEMM B-matrix, j' = u*4+g <-> gate-row g*256+u), bP, WlinQ.
// ---------------------------------------------------------------------------
__global__ void prep1_kernel(const float* __restrict__ Wih_f, const float* __restrict__ b_f,
                             const float* __restrict__ Wih_b, const float* __restrict__ b_b,
                             const float* __restrict__ Wlin,
                             float* __restrict__ WihP, float* __restrict__ bP,
                             float* __restrict__ WlinQ)
{
    int tid = blockIdx.x * blockDim.x + threadIdx.x;   // [0, 2*262144)
    int dir = tid >> 18;
    int r   = tid & 262143;
    int k   = r >> 10;        // 0..255
    int jp  = r & 1023;       // j'
    int u   = jp >> 2;
    int g   = jp & 3;
    int row = g * 256 + u;
    const float* Wih = dir ? Wih_b : Wih_f;
    const float* bv  = dir ? b_b   : b_f;
    WihP[dir * WMAT_PER_DIR + k * 1024 + jp] = Wih[row * 256 + k];
    if (r < 1024) {
        bP[dir * 1024 + jp] = bv[row];
        int uu = r >> 2, tt = r & 3;
        WlinQ[(dir * 256 + uu) * 4 + tt] = Wlin[tt * (2 * Hh) + dir * 256 + uu];
    }
}

// ---------------------------------------------------------------------------
// scale_kernel: per gate-row absmax/127. 512 blocks x 256 thr; wave = one row.
// ---------------------------------------------------------------------------
__global__ __launch_bounds__(256) void scale_kernel(const float* __restrict__ Whh_f,
                                                    const float* __restrict__ Whh_b,
                                                    float* __restrict__ scales)
{
    const int gw = blockIdx.x * 4 + (threadIdx.x >> 6);   // 0..2047
    const int lane = threadIdx.x & 63;
    const int dir = gw >> 10;
    const int row = gw & 1023;
    const float* W = dir ? Whh_b : Whh_f;
    const float* src = W + (size_t)row * 256 + lane * 4;
    float m = fmaxf(fmaxf(fabsf(src[0]), fabsf(src[1])),
                    fmaxf(fabsf(src[2]), fabsf(src[3])));
    #pragma unroll
    for (int off = 32; off > 0; off >>= 1) m = fmaxf(m, __shfl_down(m, off));
    if (lane == 0) scales[gw] = fmaxf(m, 1e-12f) / 127.f;
}

// ---------------------------------------------------------------------------
// quant_kernel: build the permuted int8 image W8. 512 x 256 = 131072 threads,
// one packed u32 each.
// ---------------------------------------------------------------------------
__global__ __launch_bounds__(256) void quant_kernel(const float* __restrict__ Whh_f,
                                                    const float* __restrict__ Whh_b,
                                                    const float* __restrict__ scales,
                                                    unsigned int* __restrict__ W8)
{
    const int idx = blockIdx.x * 256 + threadIdx.x;   // 0..131071
    const int dir = idx >> 16;
    const int rem = idx & 65535;
    int slot, t, j, kw;
    if (rem < STAT_U32) {
        slot = rem >> 11; const int r2 = rem & 2047; t = r2 >> 2; j = r2 & 3;
        kw = 2 * slot + (j >> 1);
    } else {
        const int q2 = rem - STAT_U32;
        slot = q2 >> 11; const int r2 = q2 & 2047; t = r2 >> 2; j = r2 & 3;
        kw = 36 + 2 * slot + (j >> 1);
    }
    const int rr = j & 1;
    const int u = t & 255;
    const int gs = (t < 256 ? 0 : 2) + rr;
    const int row = gs * 256 + u;
    const float* W = dir ? Whh_b : Whh_f;
    const float sc = scales[dir * 1024 + row];
    const float inv = 1.f / sc;
    unsigned int v = 0;
    #pragma unroll
    for (int i = 0; i < 4; ++i) {
        const float w = W[(size_t)row * 256 + kw * 4 + i];
        int q = (int)rintf(w * inv);
        q = q > 127 ? 127 : (q < -127 ? -127 : q);
        v |= ((unsigned int)(unsigned char)(signed char)q) << (8 * i);
    }
    W8[idx] = v;
}

// ---------------------------------------------------------------------------
// embproj GEMM: embproj[dir][v][j'] = sum_e emb[v][e]*WihP[dir][e][j'] + bP[dir][j']
// ---------------------------------------------------------------------------
#define BM 64
#define BN 128
#define BK 16
__global__ __launch_bounds__(256) void embproj_gemm(const float* __restrict__ emb,
                                                    const float* __restrict__ WihP,
                                                    const float* __restrict__ bP,
                                                    float* __restrict__ embproj)
{
    int dir = blockIdx.z;
    const float* Bmat = WihP + dir * WMAT_PER_DIR;
    float* C = embproj + (size_t)dir * EPROJ_PER_DIR;
    int m0 = blockIdx.x * BM;
    int n0 = blockIdx.y * BN;

    __shared__ float As[BK][BM];
    __shared__ float Bs[BK][BN];

    int t = threadIdx.x;
    int tm = (t & 15) * 4;
    int tn = (t >> 4) * 8;
    float acc[4][8];
    #pragma unroll
    for (int i = 0; i < 4; ++i)
        #pragma unroll
        for (int j = 0; j < 8; ++j) acc[i][j] = 0.f;

    for (int k0 = 0; k0 < Ee; k0 += BK) {
        {   // A tile 64x16
            int row = t >> 2, seg = t & 3;
            float4 a4 = *(const float4*)(&emb[(size_t)(m0 + row) * Ee + k0 + seg * 4]);
            As[seg * 4 + 0][row] = a4.x;
            As[seg * 4 + 1][row] = a4.y;
            As[seg * 4 + 2][row] = a4.z;
            As[seg * 4 + 3][row] = a4.w;
        }
        {   // B tile 16x128
            int kk = t >> 4, nn = (t & 15) * 8;
            float4 b0 = *(const float4*)(&Bmat[(size_t)(k0 + kk) * 1024 + n0 + nn]);
            float4 b1 = *(const float4*)(&Bmat[(size_t)(k0 + kk) * 1024 + n0 + nn + 4]);
            *(float4*)&Bs[kk][nn]     = b0;
            *(float4*)&Bs[kk][nn + 4] = b1;
        }
        __syncthreads();
        #pragma unroll
        for (int k = 0; k < BK; ++k) {
            float4 a  = *(const float4*)&As[k][tm];
            float4 b0 = *(const float4*)&Bs[k][tn];
            float4 b1 = *(const float4*)&Bs[k][tn + 4];
            float av[4] = {a.x, a.y, a.z, a.w};
            float bv[8] = {b0.x, b0.y, b0.z, b0.w, b1.x, b1.y, b1.z, b1.w};
            #pragma unroll
            for (int i = 0; i < 4; ++i)
                #pragma unroll
                for (int j = 0; j < 8; ++j)
                    acc[i][j] += av[i] * bv[j];
        }
        __syncthreads();
    }
    #pragma unroll
    for (int i = 0; i < 4; ++i) {
        int m = m0 + tm + i;
        #pragma unroll
        for (int j = 0; j < 8; j += 4) {
            float4 o;
            o.x = acc[i][j + 0] + bP[dir * 1024 + n0 + tn + j + 0];
            o.y = acc[i][j + 1] + bP[dir * 1024 + n0 + tn + j + 1];
            o.z = acc[i][j + 2] + bP[dir * 1024 + n0 + tn + j + 2];
            o.w = acc[i][j + 3] + bP[dir * 1024 + n0 + tn + j + 3];
            *(float4*)&C[(size_t)m * 1024 + n0 + tn + j] = o;
        }
    }
}

// ---------------------------------------------------------------------------
// R13 LSTM: SYNC-FREE. One plain WG per (dir,batch); 128 blocks x 512 thr.
// int8 weights: static 144KB in LDS (lane-linear uint4, conflict-free) +
// 112KB/step streamed from L2 as plain per-thread coalesced uint4 loads
// (weights L2-resident: 512KB/dir, shared by all WGs). Thread owns 2 gate-rows
// of unit u (low t<256: i,f; high: g,o); h packed int8 in LDS (uniform
// broadcast reads); sdot4 exact i32 accumulate; f32 activations/emission.
// Gate halves meet via 2KB LDS; 2 barriers/step. No atomics/flags/polls.
// ---------------------------------------------------------------------------
__global__ __attribute__((amdgpu_flat_work_group_size(512, 512)))
__attribute__((amdgpu_waves_per_eu(2, 2))) void lstm_stream_kernel(
    const int* __restrict__ sentence,
    const float* __restrict__ embproj,
    const unsigned int* __restrict__ W8,
    const float* __restrict__ scales,
    const float* __restrict__ WlinQ,
    float* __restrict__ emisP)
{
    extern __shared__ char smem[];
    uint4*        SWl   = (uint4*)smem;                          // 18*512 uint4 = 147456B
    unsigned int* h8    = (unsigned int*)(smem + 147456);        // 64 u32 (256 int8 h)
    float2*       part  = (float2*)(smem + 147456 + 256);        // 256 float2
    float4*       emred = (float4*)(smem + 147456 + 256 + 2048); // 4

    const int bx  = blockIdx.x;
    const int dir = bx >> 6;
    const int b   = bx & 63;
    const int t   = threadIdx.x;
    const int lane = t & 63, wv = t >> 6;
    const int u   = t & 255;
    const bool lo = (t < 256);
    const int gs0 = lo ? 0 : 2;

    const unsigned int* Wd   = W8 + (size_t)dir * 65536;
    const unsigned int* Wstr = Wd + STAT_U32;

    // stage static weight section into LDS (coalesced)
    #pragma unroll
    for (int i = 0; i < NSTAT; ++i)
        SWl[i * 512 + t] = *(const uint4*)(Wd + (size_t)(i * 512 + t) * 4);
    if (t < 64) h8[t] = 0u;   // h(-1) = 0

    const float sc0 = scales[dir * 1024 + gs0 * 256 + u] * (1.f / 127.f);
    const float sc1 = scales[dir * 1024 + (gs0 + 1) * 256 + u] * (1.f / 127.f);
    float4 wl = make_float4(0.f, 0.f, 0.f, 0.f);
    if (lo) wl = *(const float4*)&WlinQ[(dir * 256 + u) * 4];
    const float* EP = embproj + (size_t)dir * EPROJ_PER_DIR;
    const int* sent = sentence + (size_t)b * Ss;
    float c = 0.f;

    __syncthreads();

    for (int s = 0; s < Ss; ++s) {
        const int pos = dir ? (Ss - 1 - s) : s;
        const int tok = sent[pos];
        const float2 ep = *(const float2*)(EP + (size_t)tok * 1024 + u * 4 + gs0);

        // stream this thread's 28 k-words (224B) from L2 into registers
        uint4 sb[NSTRM];
        #pragma unroll
        for (int i = 0; i < NSTRM; ++i)
            sb[i] = *(const uint4*)(Wstr + (size_t)(i * 512 + t) * 4);

        int a0 = 0, a1 = 0;
        // static section (LDS) — overlaps the stream loads' latency
        #pragma unroll
        for (int i = 0; i < NSTAT; ++i) {
            const uint4 w = SWl[i * 512 + t];
            const uint2 hw = *(const uint2*)&h8[2 * i];
            a0 = dot4i8(w.x, hw.x, a0); a1 = dot4i8(w.y, hw.x, a1);
            a0 = dot4i8(w.z, hw.y, a0); a1 = dot4i8(w.w, hw.y, a1);
        }
        // streamed section (registers)
        #pragma unroll
        for (int i = 0; i < NSTRM; ++i) {
            const uint4 w = sb[i];
            const uint2 hw = *(const uint2*)&h8[36 + 2 * i];
            a0 = dot4i8(w.x, hw.x, a0); a1 = dot4i8(w.y, hw.x, a1);
            a0 = dot4i8(w.z, hw.y, a0); a1 = dot4i8(w.w, hw.y, a1);
        }

        const float g0 = (float)a0 * sc0 + ep.x;   // lo: i   | hi: g
        const float g1 = (float)a1 * sc1 + ep.y;   // lo: f   | hi: o
        if (!lo) part[u] = make_float2(g0, g1);
        __syncthreads();   // B1: part ready; all h8 reads of this step done

        if (lo) {
            const float2 pg = part[u];
            c = sigm(g1) * c + sigm(g0) * tanhf(pg.x);
            const float h = sigm(pg.y) * tanhf(c);
            // fused emission (f32 h)
            float4 em = make_float4(h * wl.x, h * wl.y, h * wl.z, h * wl.w);
            #pragma unroll
            for (int off = 32; off > 0; off >>= 1) {
                em.x += __shfl_down(em.x, off); em.y += __shfl_down(em.y, off);
                em.z += __shfl_down(em.z, off); em.w += __shfl_down(em.w, off);
            }
            if (lane == 0) emred[wv] = em;
            // publish h as int8 (|h|<1 so rint in [-127,127])
            ((char*)h8)[u] = (char)(int)rintf(h * 127.f);
        }
        __syncthreads();   // B2: h8(s) + emred visible

        if (t == 0) {
            const float4 e0 = emred[0], e1 = emred[1], e2 = emred[2], e3 = emred[3];
            float4 o;
            o.x = e0.x + e1.x + e2.x + e3.x;
            o.y = e0.y + e1.y + e2.y + e3.y;
            o.z = e0.z + e1.z + e2.z + e3.z;
            o.w = e0.w + e1.w + e2.w + e3.w;
            *(float4*)&emisP[(((size_t)dir * Ss + pos) * Bb + b) * 4] = o;
        }
    }
}

// ---------------------------------------------------------------------------
// Fused CRF + Viterbi tail. grid 8 x 64 threads. emis = emisP[0] + emisP[1].
// ---------------------------------------------------------------------------
#define EM2(S_, B_, J_) (emisA[(((size_t)(S_)) * Bb + (B_)) * 4 + (J_)] + \
                         emisB[(((size_t)(S_)) * Bb + (B_)) * 4 + (J_)])

__global__ __launch_bounds__(64) void tail_kernel(
    const float* __restrict__ emisA, const float* __restrict__ emisB,
    const float* __restrict__ blin, const float* __restrict__ start_t,
    const float* __restrict__ end_t, const float* __restrict__ trans,
    const int* __restrict__ tags, float* __restrict__ out_tags,
    float* __restrict__ out_loss)
{
    const int blk = blockIdx.x;
    const int t = threadIdx.x;
    const int b_loc = t >> 2, j = t & 3;
    const int base = t & ~3;

    if (blk < 4) {
        __shared__ unsigned char bp_sh[16][513][4];
        __shared__ unsigned char tag_sh[16][520];
        const int b = blk * 16 + b_loc;
        const float trj0 = trans[0*4+j], trj1 = trans[1*4+j],
                    trj2 = trans[2*4+j], trj3 = trans[3*4+j];
        const float blj = blin[j];
        float score = start_t[j] + EM2(0, b, j) + blj;
        for (int s = 1; s < Ss; ++s) {
            const float e = EM2(s, b, j) + blj;
            const float s0 = __shfl(score, base+0), s1 = __shfl(score, base+1),
                        s2 = __shfl(score, base+2), s3 = __shfl(score, base+3);
            float best = s0 + trj0; int bi = 0;
            float v = s1 + trj1; if (v > best) { best = v; bi = 1; }
            v = s2 + trj2; if (v > best) { best = v; bi = 2; }
            v = s3 + trj3; if (v > best) { best = v; bi = 3; }
            score = best + e;
            bp_sh[b_loc][s][j] = (unsigned char)bi;
        }
        const float fv = score + end_t[j];
        const float f0 = __shfl(fv, base+0), f1 = __shfl(fv, base+1),
                    f2 = __shfl(fv, base+2), f3 = __shfl(fv, base+3);
        __syncthreads();
        if (j == 0) {   // backtrack (first-occurrence argmax, like jnp)
            float best = f0; int tag = 0;
            if (f1 > best) { best = f1; tag = 1; }
            if (f2 > best) { best = f2; tag = 2; }
            if (f3 > best) { best = f3; tag = 3; }
            tag_sh[b_loc][Ss-1] = (unsigned char)tag;
            for (int s = Ss - 1; s >= 1; --s) {
                tag = bp_sh[b_loc][s][tag];
                tag_sh[b_loc][s-1] = (unsigned char)tag;
            }
        }
        __syncthreads();
        for (int idx = t; idx < 16 * Ss; idx += 64) {
            const int bl = idx >> 9, s = idx & (Ss - 1);
            out_tags[(size_t)(blk*16 + bl) * Ss + s] = (float)tag_sh[bl][s];
        }
    } else {
        const int b = (blk - 4) * 16 + b_loc;
        const float trj0 = trans[0*4+j], trj1 = trans[1*4+j],
                    trj2 = trans[2*4+j], trj3 = trans[3*4+j];
        const float blj = blin[j];
        float alpha = start_t[j] + EM2(0, b, j) + blj;
        for (int s = 1; s < Ss; ++s) {
            const float e = EM2(s, b, j) + blj;
            const float a0 = __shfl(alpha, base+0), a1 = __shfl(alpha, base+1),
                        a2 = __shfl(alpha, base+2), a3 = __shfl(alpha, base+3);
            const float x0 = a0 + trj0, x1 = a1 + trj1, x2 = a2 + trj2, x3 = a3 + trj3;
            const float m = fmaxf(fmaxf(x0, x1), fmaxf(x2, x3));
            alpha = m + logf(expf(x0-m) + expf(x1-m) + expf(x2-m) + expf(x3-m)) + e;
        }
        const float dv = alpha + end_t[j];
        const float d0 = __shfl(dv, base+0), d1 = __shfl(dv, base+1),
                    d2 = __shfl(dv, base+2), d3 = __shfl(dv, base+3);
        const float dm = fmaxf(fmaxf(d0, d1), fmaxf(d2, d3));
        const float denom = dm + logf(expf(d0-dm) + expf(d1-dm) + expf(d2-dm) + expf(d3-dm));

        const int lo = j * 128, hi = lo + 128;
        float num = 0.f;
        int tprev = (lo > 0) ? tags[(size_t)b*Ss + lo - 1] : 0;
        if (j == 0) num += start_t[tags[(size_t)b*Ss]];
        if (j == 3) num += end_t[tags[(size_t)b*Ss + Ss - 1]];
        for (int s = lo; s < hi; ++s) {
            const int tg = tags[(size_t)b*Ss + s];
            num += EM2(s, b, tg) + blin[tg];
            if (s > 0) num += trans[tprev*4 + tg];
            tprev = tg;
        }
        num += __shfl_xor(num, 1);
        num += __shfl_xor(num, 2);
        float lb = (j == 0) ? (denom - num) : 0.f;
        #pragma unroll
        for (int off = 32; off > 0; off >>= 1) lb += __shfl_down(lb, off);
        if (t == 0) atomicAdd(out_loss, lb);
    }
}

// ---------------------------------------------------------------------------
extern "C" void kernel_launch(void* const* d_in, const int* in_sizes, int n_in,
                              void* d_out, int out_size, void* d_ws, size_t ws_size,
                              hipStream_t stream)
{
    const int*   sentence = (const int*)d_in[0];
    const int*   tags     = (const int*)d_in[1];
    const float* emb      = (const float*)d_in[3];
    const float* Wih_f    = (const float*)d_in[4];
    const float* Whh_f    = (const float*)d_in[5];
    const float* b_f      = (const float*)d_in[6];
    const float* Wih_b    = (const float*)d_in[7];
    const float* Whh_b    = (const float*)d_in[8];
    const float* b_b      = (const float*)d_in[9];
    const float* Wlin     = (const float*)d_in[10];
    const float* blin     = (const float*)d_in[11];
    const float* start_t  = (const float*)d_in[12];
    const float* end_t    = (const float*)d_in[13];
    const float* trans    = (const float*)d_in[14];

    // workspace layout (floats)
    float*        embproj = (float*)d_ws;                      // 16,384,000
    float*        WihP    = embproj + 2 * EPROJ_PER_DIR;       // 524,288
    float*        bP      = WihP + 2 * WMAT_PER_DIR;           // 2048
    float*        WlinQ   = bP + 2048;                         // 2048
    float*        scales  = WlinQ + 2048;                      // 2048
    unsigned int* W8      = (unsigned int*)(scales + 2048);    // 131,072 u32
    float*        emisP   = (float*)(W8 + 131072);             // 2*512*64*4
    float*        emisA   = emisP;
    float*        emisB   = emisP + Ss * Bb * 4;

    prep1_kernel<<<2048, 256, 0, stream>>>(Wih_f, b_f, Wih_b, b_b, Wlin,
                                           WihP, bP, WlinQ);
    scale_kernel<<<512, 256, 0, stream>>>(Whh_f, Whh_b, scales);
    quant_kernel<<<512, 256, 0, stream>>>(Whh_f, Whh_b, scales, W8);

    dim3 gg(Vv / BM, 1024 / BN, 2);
    embproj_gemm<<<gg, 256, 0, stream>>>(emb, WihP, bP, embproj);

    lstm_stream_kernel<<<128, 512, 149824, stream>>>(sentence, embproj, W8,
                                                     scales, WlinQ, emisP);

    float* out = (float*)d_out;
    float* out_loss = out + Bb * Ss;
    hipMemsetAsync(out_loss, 0, sizeof(float), stream);
    tail_kernel<<<8, 64, 0, stream>>>(emisA, emisB, blin, start_t, end_t, trans,
                                      tags, out, out_loss);
}

// Round 14
// 1063.928 us; speedup vs baseline: 1.9611x; 1.0305x over previous
//
#include <hip/hip_runtime.h>
#include <math.h>

// Problem constants
#define Vv 8000
#define Ee 256
#define Hh 256
#define Tt 4
#define Bb 64
#define Ss 512

#define EPROJ_PER_DIR (Vv * 1024)   // 8,192,000 floats per direction
#define WMAT_PER_DIR  (Ee * 1024)   // 262,144 floats per direction

// int8 weight image geometry (per dir = 65536 u32 = 256KB):
//   64 k-words (kw) of 4 k each. static kw 0..35 (18 uint4-slots), streamed
//   kw 36..63 (14 uint4-slots). u32 at (sec, slot, t, j):
//     kw = (sec? 36:0) + 2*slot + (j>>1), rr = j&1
//     row_orig = ((t<256?0:2)+rr)*256 + (t&255)   [gate-major, as input Whh]
//   Thread t consumes uint4 (slot*512+t) -> lane-linear, coalesced/conflict-free.
#define NSTAT 18
#define NSTRM 14
#define STAT_U32 (NSTAT * 512 * 4)   // 36864

__device__ __forceinline__ float sigm(float x) { return 1.f / (1.f + expf(-x)); }

#if defined(__has_builtin)
# if __has_builtin(__builtin_amdgcn_sdot4)
#  define HAS_SDOT4 1
# endif
#endif

__device__ __forceinline__ int dot4i8(unsigned a, unsigned b, int c) {
#ifdef HAS_SDOT4
    return __builtin_amdgcn_sdot4((int)a, (int)b, c, false);
#else
    int s = c;
    #pragma unroll
    for (int i = 0; i < 4; ++i) {
        const int xa = ((int)(a << (24 - 8 * i))) >> 24;
        const int xb = ((int)(b << (24 - 8 * i))) >> 24;
        s += xa * xb;
    }
    return s;
#endif
}

// ---------------------------------------------------------------------------
// prep1: WihP (GEMM B-matrix, j' = u*4+g <-> gate-row g*256+u), bP, WlinQ.
// ---------------------------------------------------------------------------
__global__ void prep1_kernel(const float* __restrict__ Wih_f, const float* __restrict__ b_f,
                             const float* __restrict__ Wih_b, const float* __restrict__ b_b,
                             const float* __restrict__ Wlin,
                             float* __restrict__ WihP, float* __restrict__ bP,
                             float* __restrict__ WlinQ)
{
    int tid = blockIdx.x * blockDim.x + threadIdx.x;   // [0, 2*262144)
    int dir = tid >> 18;
    int r   = tid & 262143;
    int k   = r >> 10;        // 0..255
    int jp  = r & 1023;       // j'
    int u   = jp >> 2;
    int g   = jp & 3;
    int row = g * 256 + u;
    const float* Wih = dir ? Wih_b : Wih_f;
    const float* bv  = dir ? b_b   : b_f;
    WihP[dir * WMAT_PER_DIR + k * 1024 + jp] = Wih[row * 256 + k];
    if (r < 1024) {
        bP[dir * 1024 + jp] = bv[row];
        int uu = r >> 2, tt = r & 3;
        WlinQ[(dir * 256 + uu) * 4 + tt] = Wlin[tt * (2 * Hh) + dir * 256 + uu];
    }
}

// ---------------------------------------------------------------------------
// scale_kernel: per gate-row absmax/127. 512 blocks x 256 thr; wave = one row.
// ---------------------------------------------------------------------------
__global__ __launch_bounds__(256) void scale_kernel(const float* __restrict__ Whh_f,
                                                    const float* __restrict__ Whh_b,
                                                    float* __restrict__ scales)
{
    const int gw = blockIdx.x * 4 + (threadIdx.x >> 6);   // 0..2047
    const int lane = threadIdx.x & 63;
    const int dir = gw >> 10;
    const int row = gw & 1023;
    const float* W = dir ? Whh_b : Whh_f;
    const float* src = W + (size_t)row * 256 + lane * 4;
    float m = fmaxf(fmaxf(fabsf(src[0]), fabsf(src[1])),
                    fmaxf(fabsf(src[2]), fabsf(src[3])));
    #pragma unroll
    for (int off = 32; off > 0; off >>= 1) m = fmaxf(m, __shfl_down(m, off));
    if (lane == 0) scales[gw] = fmaxf(m, 1e-12f) / 127.f;
}

// ---------------------------------------------------------------------------
// quant_kernel: build the permuted int8 image W8 (as R13).
// ---------------------------------------------------------------------------
__global__ __launch_bounds__(256) void quant_kernel(const float* __restrict__ Whh_f,
                                                    const float* __restrict__ Whh_b,
                                                    const float* __restrict__ scales,
                                                    unsigned int* __restrict__ W8)
{
    const int idx = blockIdx.x * 256 + threadIdx.x;   // 0..131071
    const int dir = idx >> 16;
    const int rem = idx & 65535;
    int slot, t, j, kw;
    if (rem < STAT_U32) {
        slot = rem >> 11; const int r2 = rem & 2047; t = r2 >> 2; j = r2 & 3;
        kw = 2 * slot + (j >> 1);
    } else {
        const int q2 = rem - STAT_U32;
        slot = q2 >> 11; const int r2 = q2 & 2047; t = r2 >> 2; j = r2 & 3;
        kw = 36 + 2 * slot + (j >> 1);
    }
    const int rr = j & 1;
    const int u = t & 255;
    const int gs = (t < 256 ? 0 : 2) + rr;
    const int row = gs * 256 + u;
    const float* W = dir ? Whh_b : Whh_f;
    const float sc = scales[dir * 1024 + row];
    const float inv = 1.f / sc;
    unsigned int v = 0;
    #pragma unroll
    for (int i = 0; i < 4; ++i) {
        const float w = W[(size_t)row * 256 + kw * 4 + i];
        int q = (int)rintf(w * inv);
        q = q > 127 ? 127 : (q < -127 ? -127 : q);
        v |= ((unsigned int)(unsigned char)(signed char)q) << (8 * i);
    }
    W8[idx] = v;
}

// ---------------------------------------------------------------------------
// wl8_kernel: quantize emission weights per (dir, tag). 1 block x 512 thr;
// wave w = dir*4+t. wl8T[w][lane] packs units 4lane..4lane+3; scfac[w] =
// (max|wl|/127)/127 (wl scale x h scale).
// ---------------------------------------------------------------------------
__global__ __launch_bounds__(512) void wl8_kernel(const float* __restrict__ Wlin,
                                                  unsigned int* __restrict__ wl8T,
                                                  float* __restrict__ scfac)
{
    const int w = threadIdx.x >> 6;      // 0..7
    const int lane = threadIdx.x & 63;
    const int dir = w >> 2, t = w & 3;
    const float4 v = *(const float4*)(Wlin + t * (2 * Hh) + dir * 256 + lane * 4);
    float m = fmaxf(fmaxf(fabsf(v.x), fabsf(v.y)), fmaxf(fabsf(v.z), fabsf(v.w)));
    #pragma unroll
    for (int off = 32; off > 0; off >>= 1) m = fmaxf(m, __shfl_down(m, off));
    const float mall = __builtin_amdgcn_readfirstlane(m);
    const float sc = fmaxf(mall, 1e-12f) / 127.f;
    const float inv = 1.f / sc;
    const float vv[4] = {v.x, v.y, v.z, v.w};
    unsigned int pk = 0;
    #pragma unroll
    for (int i = 0; i < 4; ++i) {
        int q = (int)rintf(vv[i] * inv);
        q = q > 127 ? 127 : (q < -127 ? -127 : q);
        pk |= ((unsigned int)(unsigned char)(signed char)q) << (8 * i);
    }
    wl8T[w * 64 + lane] = pk;
    if (lane == 0) scfac[w] = sc / 127.f;
}

// ---------------------------------------------------------------------------
// embproj GEMM: embproj[dir][v][j'] = sum_e emb[v][e]*WihP[dir][e][j'] + bP[dir][j']
// ---------------------------------------------------------------------------
#define BM 64
#define BN 128
#define BK 16
__global__ __launch_bounds__(256) void embproj_gemm(const float* __restrict__ emb,
                                                    const float* __restrict__ WihP,
                                                    const float* __restrict__ bP,
                                                    float* __restrict__ embproj)
{
    int dir = blockIdx.z;
    const float* Bmat = WihP + dir * WMAT_PER_DIR;
    float* C = embproj + (size_t)dir * EPROJ_PER_DIR;
    int m0 = blockIdx.x * BM;
    int n0 = blockIdx.y * BN;

    __shared__ float As[BK][BM];
    __shared__ float Bs[BK][BN];

    int t = threadIdx.x;
    int tm = (t & 15) * 4;
    int tn = (t >> 4) * 8;
    float acc[4][8];
    #pragma unroll
    for (int i = 0; i < 4; ++i)
        #pragma unroll
        for (int j = 0; j < 8; ++j) acc[i][j] = 0.f;

    for (int k0 = 0; k0 < Ee; k0 += BK) {
        {   // A tile 64x16
            int row = t >> 2, seg = t & 3;
            float4 a4 = *(const float4*)(&emb[(size_t)(m0 + row) * Ee + k0 + seg * 4]);
            As[seg * 4 + 0][row] = a4.x;
            As[seg * 4 + 1][row] = a4.y;
            As[seg * 4 + 2][row] = a4.z;
            As[seg * 4 + 3][row] = a4.w;
        }
        {   // B tile 16x128
            int kk = t >> 4, nn = (t & 15) * 8;
            float4 b0 = *(const float4*)(&Bmat[(size_t)(k0 + kk) * 1024 + n0 + nn]);
            float4 b1 = *(const float4*)(&Bmat[(size_t)(k0 + kk) * 1024 + n0 + nn + 4]);
            *(float4*)&Bs[kk][nn]     = b0;
            *(float4*)&Bs[kk][nn + 4] = b1;
        }
        __syncthreads();
        #pragma unroll
        for (int k = 0; k < BK; ++k) {
            float4 a  = *(const float4*)&As[k][tm];
            float4 b0 = *(const float4*)&Bs[k][tn];
            float4 b1 = *(const float4*)&Bs[k][tn + 4];
            float av[4] = {a.x, a.y, a.z, a.w};
            float bv[8] = {b0.x, b0.y, b0.z, b0.w, b1.x, b1.y, b1.z, b1.w};
            #pragma unroll
            for (int i = 0; i < 4; ++i)
                #pragma unroll
                for (int j = 0; j < 8; ++j)
                    acc[i][j] += av[i] * bv[j];
        }
        __syncthreads();
    }
    #pragma unroll
    for (int i = 0; i < 4; ++i) {
        int m = m0 + tm + i;
        #pragma unroll
        for (int j = 0; j < 8; j += 4) {
            float4 o;
            o.x = acc[i][j + 0] + bP[dir * 1024 + n0 + tn + j + 0];
            o.y = acc[i][j + 1] + bP[dir * 1024 + n0 + tn + j + 1];
            o.z = acc[i][j + 2] + bP[dir * 1024 + n0 + tn + j + 2];
            o.w = acc[i][j + 3] + bP[dir * 1024 + n0 + tn + j + 3];
            *(float4*)&C[(size_t)m * 1024 + n0 + tn + j] = o;
        }
    }
}

// ---------------------------------------------------------------------------
// R14 LSTM: R13 sync-free structure, LDS-pipe decongested.
//  - h broadcast: ONE ds_read_b32 per wave (v_h = h8[lane]) + per-kw
//    v_readlane -> uniform SGPR operand into sdot4 (was 32 ds_read_b64/wave).
//  - emission: int8 dot on wave 4 (wl8T regs x v_h = h(s-1)) + int shfl
//    reduce; replaces the f32 shfl-reduce machinery (wave-4-only cost).
//  - accumulators split even/odd slots (shorter dependent sdot4 chains).
// ---------------------------------------------------------------------------
__global__ __attribute__((amdgpu_flat_work_group_size(512, 512)))
__attribute__((amdgpu_waves_per_eu(2, 2))) void lstm_stream_kernel(
    const int* __restrict__ sentence,
    const float* __restrict__ embproj,
    const unsigned int* __restrict__ W8,
    const float* __restrict__ scales,
    const unsigned int* __restrict__ wl8T,
    const float* __restrict__ scfac,
    float* __restrict__ emisP)
{
    extern __shared__ char smem[];
    uint4*        SWl   = (uint4*)smem;                          // 18*512 uint4 = 147456B
    unsigned int* h8    = (unsigned int*)(smem + 147456);        // 64 u32 (256 int8 h)
    float2*       part  = (float2*)(smem + 147456 + 256);        // 256 float2

    const int bx  = blockIdx.x;
    const int dir = bx >> 6;
    const int b   = bx & 63;
    const int t   = threadIdx.x;
    const int lane = t & 63, wv = t >> 6;
    const int u   = t & 255;
    const bool lo = (t < 256);
    const int gs0 = lo ? 0 : 2;

    const unsigned int* Wd   = W8 + (size_t)dir * 65536;
    const unsigned int* Wstr = Wd + STAT_U32;

    // stage static weight section into LDS (coalesced)
    #pragma unroll
    for (int i = 0; i < NSTAT; ++i)
        SWl[i * 512 + t] = *(const uint4*)(Wd + (size_t)(i * 512 + t) * 4);
    if (t < 64) h8[t] = 0u;   // h(-1) = 0

    const float sc0 = scales[dir * 1024 + gs0 * 256 + u] * (1.f / 127.f);
    const float sc1 = scales[dir * 1024 + (gs0 + 1) * 256 + u] * (1.f / 127.f);
    const float* EP = embproj + (size_t)dir * EPROJ_PER_DIR;
    const int* sent = sentence + (size_t)b * Ss;
    float c = 0.f;

    // wave-4 emission state (registers)
    unsigned int wlq0 = 0, wlq1 = 0, wlq2 = 0, wlq3 = 0;
    float4 efac = make_float4(0.f, 0.f, 0.f, 0.f);
    if (wv == 4) {
        wlq0 = wl8T[(dir * 4 + 0) * 64 + lane];
        wlq1 = wl8T[(dir * 4 + 1) * 64 + lane];
        wlq2 = wl8T[(dir * 4 + 2) * 64 + lane];
        wlq3 = wl8T[(dir * 4 + 3) * 64 + lane];
        efac = *(const float4*)&scfac[dir * 4];
    }

    __syncthreads();

    for (int s = 0; s < Ss; ++s) {
        const int pos = dir ? (Ss - 1 - s) : s;
        const int tok = sent[pos];
        const float2 ep = *(const float2*)(EP + (size_t)tok * 1024 + u * 4 + gs0);

        // one LDS broadcast word per lane: h8[lane] = h(s-1) packed int8
        const int v_h = (int)h8[lane];

        // stream this thread's 14 k-word uint4s (224B) from L2
        uint4 sb[NSTRM];
        #pragma unroll
        for (int i = 0; i < NSTRM; ++i)
            sb[i] = *(const uint4*)(Wstr + (size_t)(i * 512 + t) * 4);

        // emission of h(s-1) (wave 4 only): 4 sdot4 + int shfl reduce
        if (wv == 4 && s > 0) {
            int e0 = dot4i8(wlq0, (unsigned)v_h, 0);
            int e1 = dot4i8(wlq1, (unsigned)v_h, 0);
            int e2 = dot4i8(wlq2, (unsigned)v_h, 0);
            int e3 = dot4i8(wlq3, (unsigned)v_h, 0);
            #pragma unroll
            for (int off = 32; off > 0; off >>= 1) {
                e0 += __shfl_down(e0, off); e1 += __shfl_down(e1, off);
                e2 += __shfl_down(e2, off); e3 += __shfl_down(e3, off);
            }
            if (lane == 0) {
                const int pp = dir ? (Ss - s) : (s - 1);
                float4 o;
                o.x = (float)e0 * efac.x; o.y = (float)e1 * efac.y;
                o.z = (float)e2 * efac.z; o.w = (float)e3 * efac.w;
                *(float4*)&emisP[(((size_t)dir * Ss + pp) * Bb + b) * 4] = o;
            }
        }

        // gate dots: readlane h (uniform SGPR) x int8 weights; split chains
        int a0e = 0, a1e = 0, a0o = 0, a1o = 0;
        #pragma unroll
        for (int i = 0; i < NSTAT; ++i) {
            const uint4 w = SWl[i * 512 + t];
            const unsigned h0 = (unsigned)__builtin_amdgcn_readlane(v_h, 2 * i);
            const unsigned h1 = (unsigned)__builtin_amdgcn_readlane(v_h, 2 * i + 1);
            if (i & 1) {
                a0o = dot4i8(w.x, h0, a0o); a1o = dot4i8(w.y, h0, a1o);
                a0o = dot4i8(w.z, h1, a0o); a1o = dot4i8(w.w, h1, a1o);
            } else {
                a0e = dot4i8(w.x, h0, a0e); a1e = dot4i8(w.y, h0, a1e);
                a0e = dot4i8(w.z, h1, a0e); a1e = dot4i8(w.w, h1, a1e);
            }
        }
        #pragma unroll
        for (int i = 0; i < NSTRM; ++i) {
            const uint4 w = sb[i];
            const unsigned h0 = (unsigned)__builtin_amdgcn_readlane(v_h, 36 + 2 * i);
            const unsigned h1 = (unsigned)__builtin_amdgcn_readlane(v_h, 37 + 2 * i);
            if (i & 1) {
                a0o = dot4i8(w.x, h0, a0o); a1o = dot4i8(w.y, h0, a1o);
                a0o = dot4i8(w.z, h1, a0o); a1o = dot4i8(w.w, h1, a1o);
            } else {
                a0e = dot4i8(w.x, h0, a0e); a1e = dot4i8(w.y, h0, a1e);
                a0e = dot4i8(w.z, h1, a0e); a1e = dot4i8(w.w, h1, a1e);
            }
        }
        const int a0 = a0e + a0o, a1 = a1e + a1o;

        const float g0 = (float)a0 * sc0 + ep.x;   // lo: i   | hi: g
        const float g1 = (float)a1 * sc1 + ep.y;   // lo: f   | hi: o
        if (!lo) part[u] = make_float2(g0, g1);
        __syncthreads();   // B1: part ready; all h8 reads of this step done

        if (lo) {
            const float2 pg = part[u];
            c = sigm(g1) * c + sigm(g0) * tanhf(pg.x);
            const float h = sigm(pg.y) * tanhf(c);
            ((char*)h8)[u] = (char)(int)rintf(h * 127.f);   // |h|<1
        }
        __syncthreads();   // B2: h8(s) visible
    }

    // epilogue: emission for h(Ss-1)
    if (wv == 4) {
        const int v_h = (int)h8[lane];
        int e0 = dot4i8(wlq0, (unsigned)v_h, 0);
        int e1 = dot4i8(wlq1, (unsigned)v_h, 0);
        int e2 = dot4i8(wlq2, (unsigned)v_h, 0);
        int e3 = dot4i8(wlq3, (unsigned)v_h, 0);
        #pragma unroll
        for (int off = 32; off > 0; off >>= 1) {
            e0 += __shfl_down(e0, off); e1 += __shfl_down(e1, off);
            e2 += __shfl_down(e2, off); e3 += __shfl_down(e3, off);
        }
        if (lane == 0) {
            const int pp = dir ? 0 : (Ss - 1);
            float4 o;
            o.x = (float)e0 * efac.x; o.y = (float)e1 * efac.y;
            o.z = (float)e2 * efac.z; o.w = (float)e3 * efac.w;
            *(float4*)&emisP[(((size_t)dir * Ss + pp) * Bb + b) * 4] = o;
        }
    }
}

// ---------------------------------------------------------------------------
// Fused CRF + Viterbi tail. grid 8 x 64 threads. emis = emisP[0] + emisP[1].
// ---------------------------------------------------------------------------
#define EM2(S_, B_, J_) (emisA[(((size_t)(S_)) * Bb + (B_)) * 4 + (J_)] + \
                         emisB[(((size_t)(S_)) * Bb + (B_)) * 4 + (J_)])

__global__ __launch_bounds__(64) void tail_kernel(
    const float* __restrict__ emisA, const float* __restrict__ emisB,
    const float* __restrict__ blin, const float* __restrict__ start_t,
    const float* __restrict__ end_t, const float* __restrict__ trans,
    const int* __restrict__ tags, float* __restrict__ out_tags,
    float* __restrict__ out_loss)
{
    const int blk = blockIdx.x;
    const int t = threadIdx.x;
    const int b_loc = t >> 2, j = t & 3;
    const int base = t & ~3;

    if (blk < 4) {
        __shared__ unsigned char bp_sh[16][513][4];
        __shared__ unsigned char tag_sh[16][520];
        const int b = blk * 16 + b_loc;
        const float trj0 = trans[0*4+j], trj1 = trans[1*4+j],
                    trj2 = trans[2*4+j], trj3 = trans[3*4+j];
        const float blj = blin[j];
        float score = start_t[j] + EM2(0, b, j) + blj;
        for (int s = 1; s < Ss; ++s) {
            const float e = EM2(s, b, j) + blj;
            const float s0 = __shfl(score, base+0), s1 = __shfl(score, base+1),
                        s2 = __shfl(score, base+2), s3 = __shfl(score, base+3);
            float best = s0 + trj0; int bi = 0;
            float v = s1 + trj1; if (v > best) { best = v; bi = 1; }
            v = s2 + trj2; if (v > best) { best = v; bi = 2; }
            v = s3 + trj3; if (v > best) { best = v; bi = 3; }
            score = best + e;
            bp_sh[b_loc][s][j] = (unsigned char)bi;
        }
        const float fv = score + end_t[j];
        const float f0 = __shfl(fv, base+0), f1 = __shfl(fv, base+1),
                    f2 = __shfl(fv, base+2), f3 = __shfl(fv, base+3);
        __syncthreads();
        if (j == 0) {   // backtrack (first-occurrence argmax, like jnp)
            float best = f0; int tag = 0;
            if (f1 > best) { best = f1; tag = 1; }
            if (f2 > best) { best = f2; tag = 2; }
            if (f3 > best) { best = f3; tag = 3; }
            tag_sh[b_loc][Ss-1] = (unsigned char)tag;
            for (int s = Ss - 1; s >= 1; --s) {
                tag = bp_sh[b_loc][s][tag];
                tag_sh[b_loc][s-1] = (unsigned char)tag;
            }
        }
        __syncthreads();
        for (int idx = t; idx < 16 * Ss; idx += 64) {
            const int bl = idx >> 9, s = idx & (Ss - 1);
            out_tags[(size_t)(blk*16 + bl) * Ss + s] = (float)tag_sh[bl][s];
        }
    } else {
        const int b = (blk - 4) * 16 + b_loc;
        const float trj0 = trans[0*4+j], trj1 = trans[1*4+j],
                    trj2 = trans[2*4+j], trj3 = trans[3*4+j];
        const float blj = blin[j];
        float alpha = start_t[j] + EM2(0, b, j) + blj;
        for (int s = 1; s < Ss; ++s) {
            const float e = EM2(s, b, j) + blj;
            const float a0 = __shfl(alpha, base+0), a1 = __shfl(alpha, base+1),
                        a2 = __shfl(alpha, base+2), a3 = __shfl(alpha, base+3);
            const float x0 = a0 + trj0, x1 = a1 + trj1, x2 = a2 + trj2, x3 = a3 + trj3;
            const float m = fmaxf(fmaxf(x0, x1), fmaxf(x2, x3));
            alpha = m + logf(expf(x0-m) + expf(x1-m) + expf(x2-m) + expf(x3-m)) + e;
        }
        const float dv = alpha + end_t[j];
        const float d0 = __shfl(dv, base+0), d1 = __shfl(dv, base+1),
                    d2 = __shfl(dv, base+2), d3 = __shfl(dv, base+3);
        const float dm = fmaxf(fmaxf(d0, d1), fmaxf(d2, d3));
        const float denom = dm + logf(expf(d0-dm) + expf(d1-dm) + expf(d2-dm) + expf(d3-dm));

        const int lo = j * 128, hi = lo + 128;
        float num = 0.f;
        int tprev = (lo > 0) ? tags[(size_t)b*Ss + lo - 1] : 0;
        if (j == 0) num += start_t[tags[(size_t)b*Ss]];
        if (j == 3) num += end_t[tags[(size_t)b*Ss + Ss - 1]];
        for (int s = lo; s < hi; ++s) {
            const int tg = tags[(size_t)b*Ss + s];
            num += EM2(s, b, tg) + blin[tg];
            if (s > 0) num += trans[tprev*4 + tg];
            tprev = tg;
        }
        num += __shfl_xor(num, 1);
        num += __shfl_xor(num, 2);
        float lb = (j == 0) ? (denom - num) : 0.f;
        #pragma unroll
        for (int off = 32; off > 0; off >>= 1) lb += __shfl_down(lb, off);
        if (t == 0) atomicAdd(out_loss, lb);
    }
}

// ---------------------------------------------------------------------------
extern "C" void kernel_launch(void* const* d_in, const int* in_sizes, int n_in,
                              void* d_out, int out_size, void* d_ws, size_t ws_size,
                              hipStream_t stream)
{
    const int*   sentence = (const int*)d_in[0];
    const int*   tags     = (const int*)d_in[1];
    const float* emb      = (const float*)d_in[3];
    const float* Wih_f    = (const float*)d_in[4];
    const float* Whh_f    = (const float*)d_in[5];
    const float* b_f      = (const float*)d_in[6];
    const float* Wih_b    = (const float*)d_in[7];
    const float* Whh_b    = (const float*)d_in[8];
    const float* b_b      = (const float*)d_in[9];
    const float* Wlin     = (const float*)d_in[10];
    const float* blin     = (const float*)d_in[11];
    const float* start_t  = (const float*)d_in[12];
    const float* end_t    = (const float*)d_in[13];
    const float* trans    = (const float*)d_in[14];

    // workspace layout (floats)
    float*        embproj = (float*)d_ws;                      // 16,384,000
    float*        WihP    = embproj + 2 * EPROJ_PER_DIR;       // 524,288
    float*        bP      = WihP + 2 * WMAT_PER_DIR;           // 2048
    float*        WlinQ   = bP + 2048;                         // 2048
    float*        scales  = WlinQ + 2048;                      // 2048
    unsigned int* W8      = (unsigned int*)(scales + 2048);    // 131,072 u32
    unsigned int* wl8T    = W8 + 131072;                       // 512 u32
    float*        scfac   = (float*)(wl8T + 512);              // 8
    float*        emisP   = scfac + 56;                        // 2*512*64*4 (16B aligned)
    float*        emisA   = emisP;
    float*        emisB   = emisP + Ss * Bb * 4;

    prep1_kernel<<<2048, 256, 0, stream>>>(Wih_f, b_f, Wih_b, b_b, Wlin,
                                           WihP, bP, WlinQ);
    scale_kernel<<<512, 256, 0, stream>>>(Whh_f, Whh_b, scales);
    quant_kernel<<<512, 256, 0, stream>>>(Whh_f, Whh_b, scales, W8);
    wl8_kernel<<<1, 512, 0, stream>>>(Wlin, wl8T, scfac);

    dim3 gg(Vv / BM, 1024 / BN, 2);
    embproj_gemm<<<gg, 256, 0, stream>>>(emb, WihP, bP, embproj);

    lstm_stream_kernel<<<128, 512, 149760, stream>>>(sentence, embproj, W8,
                                                     scales, wl8T, scfac, emisP);

    float* out = (float*)d_out;
    float* out_loss = out + Bb * Ss;
    hipMemsetAsync(out_loss, 0, sizeof(float), stream);
    tail_kernel<<<8, 64, 0, stream>>>(emisA, emisB, blin, start_t, end_t, trans,
                                      tags, out, out_loss);
}

// Round 15
// 1062.486 us; speedup vs baseline: 1.9638x; 1.0014x over previous
//
#include <hip/hip_runtime.h>
#include <math.h>

// Problem constants
#define Vv 8000
#define Ee 256
#define Hh 256
#define Tt 4
#define Bb 64
#define Ss 512

#define EPROJ_PER_DIR (Vv * 1024)   // 8,192,000 floats per direction
#define WMAT_PER_DIR  (Ee * 1024)   // 262,144 floats per direction

// int8 weight image geometry (per dir = 65536 u32 = 256KB):
//   64 k-words (kw) of 4 k each. LDS-static kw 0..2*NSTAT-1, register-hoisted
//   "stream" kw 2*NSTAT..63. u32 at (sec, slot, t, j):
//     kw = (sec? 2*NSTAT:0) + 2*slot + (j>>1), rr = j&1
//     PAIR-LANE mapping (R15): u = t>>1, gs = (t&1)*2 + rr
//     row_orig = gs*256 + u   [gate-major, as input Whh]
//   Thread t consumes uint4 (slot*512+t) -> lane-linear, coalesced/conflict-free.
#define NSTAT 8
#define NSTRM 24
#define STAT_U32 (NSTAT * 512 * 4)   // 16384

__device__ __forceinline__ float sigm(float x) { return 1.f / (1.f + expf(-x)); }

#if defined(__has_builtin)
# if __has_builtin(__builtin_amdgcn_sdot4)
#  define HAS_SDOT4 1
# endif
#endif

__device__ __forceinline__ int dot4i8(unsigned a, unsigned b, int c) {
#ifdef HAS_SDOT4
    return __builtin_amdgcn_sdot4((int)a, (int)b, c, false);
#else
    int s = c;
    #pragma unroll
    for (int i = 0; i < 4; ++i) {
        const int xa = ((int)(a << (24 - 8 * i))) >> 24;
        const int xb = ((int)(b << (24 - 8 * i))) >> 24;
        s += xa * xb;
    }
    return s;
#endif
}

// ---------------------------------------------------------------------------
// prep1: WihP (GEMM B-matrix, j' = u*4+g <-> gate-row g*256+u), bP, WlinQ.
// ---------------------------------------------------------------------------
__global__ void prep1_kernel(const float* __restrict__ Wih_f, const float* __restrict__ b_f,
                             const float* __restrict__ Wih_b, const float* __restrict__ b_b,
                             const float* __restrict__ Wlin,
                             float* __restrict__ WihP, float* __restrict__ bP,
                             float* __restrict__ WlinQ)
{
    int tid = blockIdx.x * blockDim.x + threadIdx.x;   // [0, 2*262144)
    int dir = tid >> 18;
    int r   = tid & 262143;
    int k   = r >> 10;        // 0..255
    int jp  = r & 1023;       // j'
    int u   = jp >> 2;
    int g   = jp & 3;
    int row = g * 256 + u;
    const float* Wih = dir ? Wih_b : Wih_f;
    const float* bv  = dir ? b_b   : b_f;
    WihP[dir * WMAT_PER_DIR + k * 1024 + jp] = Wih[row * 256 + k];
    if (r < 1024) {
        bP[dir * 1024 + jp] = bv[row];
        int uu = r >> 2, tt = r & 3;
        WlinQ[(dir * 256 + uu) * 4 + tt] = Wlin[tt * (2 * Hh) + dir * 256 + uu];
    }
}

// ---------------------------------------------------------------------------
// scale_kernel: per gate-row absmax/127. 512 blocks x 256 thr; wave = one row.
// ---------------------------------------------------------------------------
__global__ __launch_bounds__(256) void scale_kernel(const float* __restrict__ Whh_f,
                                                    const float* __restrict__ Whh_b,
                                                    float* __restrict__ scales)
{
    const int gw = blockIdx.x * 4 + (threadIdx.x >> 6);   // 0..2047
    const int lane = threadIdx.x & 63;
    const int dir = gw >> 10;
    const int row = gw & 1023;
    const float* W = dir ? Whh_b : Whh_f;
    const float* src = W + (size_t)row * 256 + lane * 4;
    float m = fmaxf(fmaxf(fabsf(src[0]), fabsf(src[1])),
                    fmaxf(fabsf(src[2]), fabsf(src[3])));
    #pragma unroll
    for (int off = 32; off > 0; off >>= 1) m = fmaxf(m, __shfl_down(m, off));
    if (lane == 0) scales[gw] = fmaxf(m, 1e-12f) / 127.f;
}

// ---------------------------------------------------------------------------
// quant_kernel: build the permuted int8 image W8 (pair-lane mapping).
// ---------------------------------------------------------------------------
__global__ __launch_bounds__(256) void quant_kernel(const float* __restrict__ Whh_f,
                                                    const float* __restrict__ Whh_b,
                                                    const float* __restrict__ scales,
                                                    unsigned int* __restrict__ W8)
{
    const int idx = blockIdx.x * 256 + threadIdx.x;   // 0..131071
    const int dir = idx >> 16;
    const int rem = idx & 65535;
    int slot, t, j, kw;
    if (rem < STAT_U32) {
        slot = rem >> 11; const int r2 = rem & 2047; t = r2 >> 2; j = r2 & 3;
        kw = 2 * slot + (j >> 1);
    } else {
        const int q2 = rem - STAT_U32;
        slot = q2 >> 11; const int r2 = q2 & 2047; t = r2 >> 2; j = r2 & 3;
        kw = 2 * NSTAT + 2 * slot + (j >> 1);
    }
    const int rr = j & 1;
    const int u  = t >> 1;                 // pair-lane mapping
    const int gs = (t & 1) * 2 + rr;
    const int row = gs * 256 + u;
    const float* W = dir ? Whh_b : Whh_f;
    const float sc = scales[dir * 1024 + row];
    const float inv = 1.f / sc;
    unsigned int v = 0;
    #pragma unroll
    for (int i = 0; i < 4; ++i) {
        const float w = W[(size_t)row * 256 + kw * 4 + i];
        int q = (int)rintf(w * inv);
        q = q > 127 ? 127 : (q < -127 ? -127 : q);
        v |= ((unsigned int)(unsigned char)(signed char)q) << (8 * i);
    }
    W8[idx] = v;
}

// ---------------------------------------------------------------------------
// wl8_kernel: quantize emission weights per (dir, tag). 1 block x 512 thr.
// ---------------------------------------------------------------------------
__global__ __launch_bounds__(512) void wl8_kernel(const float* __restrict__ Wlin,
                                                  unsigned int* __restrict__ wl8T,
                                                  float* __restrict__ scfac)
{
    const int w = threadIdx.x >> 6;      // 0..7
    const int lane = threadIdx.x & 63;
    const int dir = w >> 2, t = w & 3;
    const float4 v = *(const float4*)(Wlin + t * (2 * Hh) + dir * 256 + lane * 4);
    float m = fmaxf(fmaxf(fabsf(v.x), fabsf(v.y)), fmaxf(fabsf(v.z), fabsf(v.w)));
    #pragma unroll
    for (int off = 32; off > 0; off >>= 1) m = fmaxf(m, __shfl_down(m, off));
    const float mall = __builtin_amdgcn_readfirstlane(m);
    const float sc = fmaxf(mall, 1e-12f) / 127.f;
    const float inv = 1.f / sc;
    const float vv[4] = {v.x, v.y, v.z, v.w};
    unsigned int pk = 0;
    #pragma unroll
    for (int i = 0; i < 4; ++i) {
        int q = (int)rintf(vv[i] * inv);
        q = q > 127 ? 127 : (q < -127 ? -127 : q);
        pk |= ((unsigned int)(unsigned char)(signed char)q) << (8 * i);
    }
    wl8T[w * 64 + lane] = pk;
    if (lane == 0) scfac[w] = sc / 127.f;
}

// ---------------------------------------------------------------------------
// embproj GEMM: embproj[dir][v][j'] = sum_e emb[v][e]*WihP[dir][e][j'] + bP[dir][j']
// ---------------------------------------------------------------------------
#define BM 64
#define BN 128
#define BK 16
__global__ __launch_bounds__(256) void embproj_gemm(const float* __restrict__ emb,
                                                    const float* __restrict__ WihP,
                                                    const float* __restrict__ bP,
                                                    float* __restrict__ embproj)
{
    int dir = blockIdx.z;
    const float* Bmat = WihP + dir * WMAT_PER_DIR;
    float* C = embproj + (size_t)dir * EPROJ_PER_DIR;
    int m0 = blockIdx.x * BM;
    int n0 = blockIdx.y * BN;

    __shared__ float As[BK][BM];
    __shared__ float Bs[BK][BN];

    int t = threadIdx.x;
    int tm = (t & 15) * 4;
    int tn = (t >> 4) * 8;
    float acc[4][8];
    #pragma unroll
    for (int i = 0; i < 4; ++i)
        #pragma unroll
        for (int j = 0; j < 8; ++j) acc[i][j] = 0.f;

    for (int k0 = 0; k0 < Ee; k0 += BK) {
        {   // A tile 64x16
            int row = t >> 2, seg = t & 3;
            float4 a4 = *(const float4*)(&emb[(size_t)(m0 + row) * Ee + k0 + seg * 4]);
            As[seg * 4 + 0][row] = a4.x;
            As[seg * 4 + 1][row] = a4.y;
            As[seg * 4 + 2][row] = a4.z;
            As[seg * 4 + 3][row] = a4.w;
        }
        {   // B tile 16x128
            int kk = t >> 4, nn = (t & 15) * 8;
            float4 b0 = *(const float4*)(&Bmat[(size_t)(k0 + kk) * 1024 + n0 + nn]);
            float4 b1 = *(const float4*)(&Bmat[(size_t)(k0 + kk) * 1024 + n0 + nn + 4]);
            *(float4*)&Bs[kk][nn]     = b0;
            *(float4*)&Bs[kk][nn + 4] = b1;
        }
        __syncthreads();
        #pragma unroll
        for (int k = 0; k < BK; ++k) {
            float4 a  = *(const float4*)&As[k][tm];
            float4 b0 = *(const float4*)&Bs[k][tn];
            float4 b1 = *(const float4*)&Bs[k][tn + 4];
            float av[4] = {a.x, a.y, a.z, a.w};
            float bv[8] = {b0.x, b0.y, b0.z, b0.w, b1.x, b1.y, b1.z, b1.w};
            #pragma unroll
            for (int i = 0; i < 4; ++i)
                #pragma unroll
                for (int j = 0; j < 8; ++j)
                    acc[i][j] += av[i] * bv[j];
        }
        __syncthreads();
    }
    #pragma unroll
    for (int i = 0; i < 4; ++i) {
        int m = m0 + tm + i;
        #pragma unroll
        for (int j = 0; j < 8; j += 4) {
            float4 o;
            o.x = acc[i][j + 0] + bP[dir * 1024 + n0 + tn + j + 0];
            o.y = acc[i][j + 1] + bP[dir * 1024 + n0 + tn + j + 1];
            o.z = acc[i][j + 2] + bP[dir * 1024 + n0 + tn + j + 2];
            o.w = acc[i][j + 3] + bP[dir * 1024 + n0 + tn + j + 3];
            *(float4*)&C[(size_t)m * 1024 + n0 + tn + j] = o;
        }
    }
}

// ---------------------------------------------------------------------------
// R15 LSTM: sync-free (R13/R14 lineage), LDS nearly emptied + 1 barrier/step.
//  - NSTAT 8 (64KB LDS), 24 slots loop-invariant -> compiler hoists into
//    ~96 VGPRs (R14 evidence: VGPR 88 w/ 14 slots hoisted, FETCH shows no
//    per-step re-stream). Hard cap waves_per_eu(2,2) keeps the budget.
//  - PAIR-LANE gates: unit u owned by lanes (2u even: i,f | 2u+1 odd: g,o);
//    halves meet via __shfl_xor(.,1) -- part[] LDS and its barrier deleted.
//  - h8 double-buffered (write slot s&1, read slot (s-1)&1); ONE barrier
//    per step separates step-s reads from step-s+1 writes.
// ---------------------------------------------------------------------------
__global__ __attribute__((amdgpu_flat_work_group_size(512, 512)))
__attribute__((amdgpu_waves_per_eu(2, 2))) void lstm_stream_kernel(
    const int* __restrict__ sentence,
    const float* __restrict__ embproj,
    const unsigned int* __restrict__ W8,
    const float* __restrict__ scales,
    const unsigned int* __restrict__ wl8T,
    const float* __restrict__ scfac,
    float* __restrict__ emisP)
{
    extern __shared__ char smem[];
    uint4*        SWl = (uint4*)smem;                       // NSTAT*512 uint4 = 64KB
    unsigned int* h8  = (unsigned int*)(smem + STAT_U32*4); // [2][64] u32

    const int bx  = blockIdx.x;
    const int dir = bx >> 6;
    const int b   = bx & 63;
    const int t   = threadIdx.x;
    const int lane = t & 63, wv = t >> 6;
    const int u    = t >> 1;            // pair-lane unit
    const int gs0  = (t & 1) * 2;       // 0: rows i,f | 2: rows g,o
    const bool ev  = !(t & 1);

    const unsigned int* Wd   = W8 + (size_t)dir * 65536;
    const unsigned int* Wstr = Wd + STAT_U32;

    // stage static weight section into LDS (coalesced)
    #pragma unroll
    for (int i = 0; i < NSTAT; ++i)
        SWl[i * 512 + t] = *(const uint4*)(Wd + (size_t)(i * 512 + t) * 4);
    if (t < 128) h8[t] = 0u;   // h(-1) = 0, both parity slots

    // loop-invariant "streamed" slots -> registers (compiler hoists)
    uint4 sb[NSTRM];
    #pragma unroll
    for (int i = 0; i < NSTRM; ++i)
        sb[i] = *(const uint4*)(Wstr + (size_t)(i * 512 + t) * 4);

    const float sc0 = scales[dir * 1024 + (gs0 + 0) * 256 + u] * (1.f / 127.f);
    const float sc1 = scales[dir * 1024 + (gs0 + 1) * 256 + u] * (1.f / 127.f);
    const float* EP = embproj + (size_t)dir * EPROJ_PER_DIR;
    const int* sent = sentence + (size_t)b * Ss;
    float c = 0.f;

    // wave-4 emission state (registers)
    unsigned int wlq0 = 0, wlq1 = 0, wlq2 = 0, wlq3 = 0;
    float4 efac = make_float4(0.f, 0.f, 0.f, 0.f);
    if (wv == 4) {
        wlq0 = wl8T[(dir * 4 + 0) * 64 + lane];
        wlq1 = wl8T[(dir * 4 + 1) * 64 + lane];
        wlq2 = wl8T[(dir * 4 + 2) * 64 + lane];
        wlq3 = wl8T[(dir * 4 + 3) * 64 + lane];
        efac = *(const float4*)&scfac[dir * 4];
    }

    __syncthreads();

    for (int s = 0; s < Ss; ++s) {
        const int pos = dir ? (Ss - 1 - s) : s;
        const int tok = sent[pos];
        const float2 ep = *(const float2*)(EP + (size_t)tok * 1024 + u * 4 + gs0);

        const int rp = (s + 1) & 1;        // slot holding h(s-1)
        const int wp = s & 1;              // slot to write h(s)
        const int v_h = (int)h8[rp * 64 + lane];

        // emission of h(s-1) (wave 4 only): 4 sdot4 + int shfl reduce
        if (wv == 4 && s > 0) {
            int e0 = dot4i8(wlq0, (unsigned)v_h, 0);
            int e1 = dot4i8(wlq1, (unsigned)v_h, 0);
            int e2 = dot4i8(wlq2, (unsigned)v_h, 0);
            int e3 = dot4i8(wlq3, (unsigned)v_h, 0);
            #pragma unroll
            for (int off = 32; off > 0; off >>= 1) {
                e0 += __shfl_down(e0, off); e1 += __shfl_down(e1, off);
                e2 += __shfl_down(e2, off); e3 += __shfl_down(e3, off);
            }
            if (lane == 0) {
                const int pp = dir ? (Ss - s) : (s - 1);
                float4 o;
                o.x = (float)e0 * efac.x; o.y = (float)e1 * efac.y;
                o.z = (float)e2 * efac.z; o.w = (float)e3 * efac.w;
                *(float4*)&emisP[(((size_t)dir * Ss + pp) * Bb + b) * 4] = o;
            }
        }

        // gate dots: readlane h (uniform SGPR) x int8 weights; split chains
        int a0e = 0, a1e = 0, a0o = 0, a1o = 0;
        #pragma unroll
        for (int i = 0; i < NSTAT; ++i) {
            const uint4 w = SWl[i * 512 + t];
            const unsigned h0 = (unsigned)__builtin_amdgcn_readlane(v_h, 2 * i);
            const unsigned h1 = (unsigned)__builtin_amdgcn_readlane(v_h, 2 * i + 1);
            if (i & 1) {
                a0o = dot4i8(w.x, h0, a0o); a1o = dot4i8(w.y, h0, a1o);
                a0o = dot4i8(w.z, h1, a0o); a1o = dot4i8(w.w, h1, a1o);
            } else {
                a0e = dot4i8(w.x, h0, a0e); a1e = dot4i8(w.y, h0, a1e);
                a0e = dot4i8(w.z, h1, a0e); a1e = dot4i8(w.w, h1, a1e);
            }
        }
        #pragma unroll
        for (int i = 0; i < NSTRM; ++i) {
            const uint4 w = sb[i];
            const unsigned h0 = (unsigned)__builtin_amdgcn_readlane(v_h, 2 * NSTAT + 2 * i);
            const unsigned h1 = (unsigned)__builtin_amdgcn_readlane(v_h, 2 * NSTAT + 2 * i + 1);
            if (i & 1) {
                a0o = dot4i8(w.x, h0, a0o); a1o = dot4i8(w.y, h0, a1o);
                a0o = dot4i8(w.z, h1, a0o); a1o = dot4i8(w.w, h1, a1o);
            } else {
                a0e = dot4i8(w.x, h0, a0e); a1e = dot4i8(w.y, h0, a1e);
                a0e = dot4i8(w.z, h1, a0e); a1e = dot4i8(w.w, h1, a1e);
            }
        }
        const int a0 = a0e + a0o, a1 = a1e + a1o;

        const float g0 = (float)a0 * sc0 + ep.x;   // ev: i  | odd: g
        const float g1 = (float)a1 * sc1 + ep.y;   // ev: f  | odd: o
        // pair exchange: even lane gets (g,o) from odd partner
        const float pg0 = __shfl_xor(g0, 1);
        const float pg1 = __shfl_xor(g1, 1);
        if (ev) {
            c = sigm(g1) * c + sigm(g0) * tanhf(pg0);
            const float h = sigm(pg1) * tanhf(c);
            ((char*)h8)[wp * 256 + u] = (char)(int)rintf(h * 127.f);   // |h|<1
        }
        __syncthreads();   // separates step-s h8 reads from step-s+1 writes
    }

    // epilogue: emission for h(Ss-1)
    if (wv == 4) {
        const int v_h = (int)h8[((Ss - 1) & 1) * 64 + lane];
        int e0 = dot4i8(wlq0, (unsigned)v_h, 0);
        int e1 = dot4i8(wlq1, (unsigned)v_h, 0);
        int e2 = dot4i8(wlq2, (unsigned)v_h, 0);
        int e3 = dot4i8(wlq3, (unsigned)v_h, 0);
        #pragma unroll
        for (int off = 32; off > 0; off >>= 1) {
            e0 += __shfl_down(e0, off); e1 += __shfl_down(e1, off);
            e2 += __shfl_down(e2, off); e3 += __shfl_down(e3, off);
        }
        if (lane == 0) {
            const int pp = dir ? 0 : (Ss - 1);
            float4 o;
            o.x = (float)e0 * efac.x; o.y = (float)e1 * efac.y;
            o.z = (float)e2 * efac.z; o.w = (float)e3 * efac.w;
            *(float4*)&emisP[(((size_t)dir * Ss + pp) * Bb + b) * 4] = o;
        }
    }
}

// ---------------------------------------------------------------------------
// Fused CRF + Viterbi tail. grid 8 x 64 threads. emis = emisP[0] + emisP[1].
// ---------------------------------------------------------------------------
#define EM2(S_, B_, J_) (emisA[(((size_t)(S_)) * Bb + (B_)) * 4 + (J_)] + \
                         emisB[(((size_t)(S_)) * Bb + (B_)) * 4 + (J_)])

__global__ __launch_bounds__(64) void tail_kernel(
    const float* __restrict__ emisA, const float* __restrict__ emisB,
    const float* __restrict__ blin, const float* __restrict__ start_t,
    const float* __restrict__ end_t, const float* __restrict__ trans,
    const int* __restrict__ tags, float* __restrict__ out_tags,
    float* __restrict__ out_loss)
{
    const int blk = blockIdx.x;
    const int t = threadIdx.x;
    const int b_loc = t >> 2, j = t & 3;
    const int base = t & ~3;

    if (blk < 4) {
        __shared__ unsigned char bp_sh[16][513][4];
        __shared__ unsigned char tag_sh[16][520];
        const int b = blk * 16 + b_loc;
        const float trj0 = trans[0*4+j], trj1 = trans[1*4+j],
                    trj2 = trans[2*4+j], trj3 = trans[3*4+j];
        const float blj = blin[j];
        float score = start_t[j] + EM2(0, b, j) + blj;
        for (int s = 1; s < Ss; ++s) {
            const float e = EM2(s, b, j) + blj;
            const float s0 = __shfl(score, base+0), s1 = __shfl(score, base+1),
                        s2 = __shfl(score, base+2), s3 = __shfl(score, base+3);
            float best = s0 + trj0; int bi = 0;
            float v = s1 + trj1; if (v > best) { best = v; bi = 1; }
            v = s2 + trj2; if (v > best) { best = v; bi = 2; }
            v = s3 + trj3; if (v > best) { best = v; bi = 3; }
            score = best + e;
            bp_sh[b_loc][s][j] = (unsigned char)bi;
        }
        const float fv = score + end_t[j];
        const float f0 = __shfl(fv, base+0), f1 = __shfl(fv, base+1),
                    f2 = __shfl(fv, base+2), f3 = __shfl(fv, base+3);
        __syncthreads();
        if (j == 0) {   // backtrack (first-occurrence argmax, like jnp)
            float best = f0; int tag = 0;
            if (f1 > best) { best = f1; tag = 1; }
            if (f2 > best) { best = f2; tag = 2; }
            if (f3 > best) { best = f3; tag = 3; }
            tag_sh[b_loc][Ss-1] = (unsigned char)tag;
            for (int s = Ss - 1; s >= 1; --s) {
                tag = bp_sh[b_loc][s][tag];
                tag_sh[b_loc][s-1] = (unsigned char)tag;
            }
        }
        __syncthreads();
        for (int idx = t; idx < 16 * Ss; idx += 64) {
            const int bl = idx >> 9, s = idx & (Ss - 1);
            out_tags[(size_t)(blk*16 + bl) * Ss + s] = (float)tag_sh[bl][s];
        }
    } else {
        const int b = (blk - 4) * 16 + b_loc;
        const float trj0 = trans[0*4+j], trj1 = trans[1*4+j],
                    trj2 = trans[2*4+j], trj3 = trans[3*4+j];
        const float blj = blin[j];
        float alpha = start_t[j] + EM2(0, b, j) + blj;
        for (int s = 1; s < Ss; ++s) {
            const float e = EM2(s, b, j) + blj;
            const float a0 = __shfl(alpha, base+0), a1 = __shfl(alpha, base+1),
                        a2 = __shfl(alpha, base+2), a3 = __shfl(alpha, base+3);
            const float x0 = a0 + trj0, x1 = a1 + trj1, x2 = a2 + trj2, x3 = a3 + trj3;
            const float m = fmaxf(fmaxf(x0, x1), fmaxf(x2, x3));
            alpha = m + logf(expf(x0-m) + expf(x1-m) + expf(x2-m) + expf(x3-m)) + e;
        }
        const float dv = alpha + end_t[j];
        const float d0 = __shfl(dv, base+0), d1 = __shfl(dv, base+1),
                    d2 = __shfl(dv, base+2), d3 = __shfl(dv, base+3);
        const float dm = fmaxf(fmaxf(d0, d1), fmaxf(d2, d3));
        const float denom = dm + logf(expf(d0-dm) + expf(d1-dm) + expf(d2-dm) + expf(d3-dm));

        const int lo = j * 128, hi = lo + 128;
        float num = 0.f;
        int tprev = (lo > 0) ? tags[(size_t)b*Ss + lo - 1] : 0;
        if (j == 0) num += start_t[tags[(size_t)b*Ss]];
        if (j == 3) num += end_t[tags[(size_t)b*Ss + Ss - 1]];
        for (int s = lo; s < hi; ++s) {
            const int tg = tags[(size_t)b*Ss + s];
            num += EM2(s, b, tg) + blin[tg];
            if (s > 0) num += trans[tprev*4 + tg];
            tprev = tg;
        }
        num += __shfl_xor(num, 1);
        num += __shfl_xor(num, 2);
        float lb = (j == 0) ? (denom - num) : 0.f;
        #pragma unroll
        for (int off = 32; off > 0; off >>= 1) lb += __shfl_down(lb, off);
        if (t == 0) atomicAdd(out_loss, lb);
    }
}

// ---------------------------------------------------------------------------
extern "C" void kernel_launch(void* const* d_in, const int* in_sizes, int n_in,
                              void* d_out, int out_size, void* d_ws, size_t ws_size,
                              hipStream_t stream)
{
    const int*   sentence = (const int*)d_in[0];
    const int*   tags     = (const int*)d_in[1];
    const float* emb      = (const float*)d_in[3];
    const float* Wih_f    = (const float*)d_in[4];
    const float* Whh_f    = (const float*)d_in[5];
    const float* b_f      = (const float*)d_in[6];
    const float* Wih_b    = (const float*)d_in[7];
    const float* Whh_b    = (const float*)d_in[8];
    const float* b_b      = (const float*)d_in[9];
    const float* Wlin     = (const float*)d_in[10];
    const float* blin     = (const float*)d_in[11];
    const float* start_t  = (const float*)d_in[12];
    const float* end_t    = (const float*)d_in[13];
    const float* trans    = (const float*)d_in[14];

    // workspace layout (floats)
    float*        embproj = (float*)d_ws;                      // 16,384,000
    float*        WihP    = embproj + 2 * EPROJ_PER_DIR;       // 524,288
    float*        bP      = WihP + 2 * WMAT_PER_DIR;           // 2048
    float*        WlinQ   = bP + 2048;                         // 2048
    float*        scales  = WlinQ + 2048;                      // 2048
    unsigned int* W8      = (unsigned int*)(scales + 2048);    // 131,072 u32
    unsigned int* wl8T    = W8 + 131072;                       // 512 u32
    float*        scfac   = (float*)(wl8T + 512);              // 8
    float*        emisP   = scfac + 56;                        // 2*512*64*4 (16B aligned)
    float*        emisA   = emisP;
    float*        emisB   = emisP + Ss * Bb * 4;

    prep1_kernel<<<2048, 256, 0, stream>>>(Wih_f, b_f, Wih_b, b_b, Wlin,
                                           WihP, bP, WlinQ);
    scale_kernel<<<512, 256, 0, stream>>>(Whh_f, Whh_b, scales);
    quant_kernel<<<512, 256, 0, stream>>>(Whh_f, Whh_b, scales, W8);
    wl8_kernel<<<1, 512, 0, stream>>>(Wlin, wl8T, scfac);

    dim3 gg(Vv / BM, 1024 / BN, 2);
    embproj_gemm<<<gg, 256, 0, stream>>>(emb, WihP, bP, embproj);

    lstm_stream_kernel<<<128, 512, STAT_U32 * 4 + 512, stream>>>(
        sentence, embproj, W8, scales, wl8T, scfac, emisP);

    float* out = (float*)d_out;
    float* out_loss = out + Bb * Ss;
    hipMemsetAsync(out_loss, 0, sizeof(float), stream);
    tail_kernel<<<8, 64, 0, stream>>>(emisA, emisB, blin, start_t, end_t, trans,
                                      tags, out, out_loss);
}

// Round 16
// 1059.052 us; speedup vs baseline: 1.9701x; 1.0032x over previous
//
#include <hip/hip_runtime.h>
#include <math.h>

// Problem constants
#define Vv 8000
#define Ee 256
#define Hh 256
#define Tt 4
#define Bb 64
#define Ss 512

#define EPROJ_PER_DIR (Vv * 1024)   // 8,192,000 floats per direction
#define WMAT_PER_DIR  (Ee * 1024)   // 262,144 floats per direction

// int8 weight image geometry (per dir = 65536 u32 = 256KB):
//   64 k-words (kw) of 4 k each. LDS-static kw 0..2*NSTAT-1, register-pinned
//   "stream" kw 2*NSTAT..63. u32 at (sec, slot, t, j):
//     kw = (sec? 2*NSTAT:0) + 2*slot + (j>>1), rr = j&1
//     PAIR-LANE mapping: u = t>>1, gs = (t&1)*2 + rr
//     row_orig = gs*256 + u   [gate-major, as input Whh]
//   Thread t consumes uint4 (slot*512+t) -> lane-linear, coalesced/conflict-free.
#define NSTAT 8
#define NSTRM 24
#define STAT_U32 (NSTAT * 512 * 4)   // 16384

__device__ __forceinline__ float sigm(float x) { return 1.f / (1.f + expf(-x)); }

#if defined(__has_builtin)
# if __has_builtin(__builtin_amdgcn_sdot4)
#  define HAS_SDOT4 1
# endif
#endif

__device__ __forceinline__ int dot4i8(unsigned a, unsigned b, int c) {
#ifdef HAS_SDOT4
    return __builtin_amdgcn_sdot4((int)a, (int)b, c, false);
#else
    int s = c;
    #pragma unroll
    for (int i = 0; i < 4; ++i) {
        const int xa = ((int)(a << (24 - 8 * i))) >> 24;
        const int xb = ((int)(b << (24 - 8 * i))) >> 24;
        s += xa * xb;
    }
    return s;
#endif
}

// ---------------------------------------------------------------------------
// prep1: WihP (GEMM B-matrix, j' = u*4+g <-> gate-row g*256+u), bP, WlinQ.
// ---------------------------------------------------------------------------
__global__ void prep1_kernel(const float* __restrict__ Wih_f, const float* __restrict__ b_f,
                             const float* __restrict__ Wih_b, const float* __restrict__ b_b,
                             const float* __restrict__ Wlin,
                             float* __restrict__ WihP, float* __restrict__ bP,
                             float* __restrict__ WlinQ)
{
    int tid = blockIdx.x * blockDim.x + threadIdx.x;   // [0, 2*262144)
    int dir = tid >> 18;
    int r   = tid & 262143;
    int k   = r >> 10;        // 0..255
    int jp  = r & 1023;       // j'
    int u   = jp >> 2;
    int g   = jp & 3;
    int row = g * 256 + u;
    const float* Wih = dir ? Wih_b : Wih_f;
    const float* bv  = dir ? b_b   : b_f;
    WihP[dir * WMAT_PER_DIR + k * 1024 + jp] = Wih[row * 256 + k];
    if (r < 1024) {
        bP[dir * 1024 + jp] = bv[row];
        int uu = r >> 2, tt = r & 3;
        WlinQ[(dir * 256 + uu) * 4 + tt] = Wlin[tt * (2 * Hh) + dir * 256 + uu];
    }
}

// ---------------------------------------------------------------------------
// scale_kernel: per gate-row absmax/127. 512 blocks x 256 thr; wave = one row.
// ---------------------------------------------------------------------------
__global__ __launch_bounds__(256) void scale_kernel(const float* __restrict__ Whh_f,
                                                    const float* __restrict__ Whh_b,
                                                    float* __restrict__ scales)
{
    const int gw = blockIdx.x * 4 + (threadIdx.x >> 6);   // 0..2047
    const int lane = threadIdx.x & 63;
    const int dir = gw >> 10;
    const int row = gw & 1023;
    const float* W = dir ? Whh_b : Whh_f;
    const float* src = W + (size_t)row * 256 + lane * 4;
    float m = fmaxf(fmaxf(fabsf(src[0]), fabsf(src[1])),
                    fmaxf(fabsf(src[2]), fabsf(src[3])));
    #pragma unroll
    for (int off = 32; off > 0; off >>= 1) m = fmaxf(m, __shfl_down(m, off));
    if (lane == 0) scales[gw] = fmaxf(m, 1e-12f) / 127.f;
}

// ---------------------------------------------------------------------------
// quant_kernel: build the permuted int8 image W8 (pair-lane mapping).
// ---------------------------------------------------------------------------
__global__ __launch_bounds__(256) void quant_kernel(const float* __restrict__ Whh_f,
                                                    const float* __restrict__ Whh_b,
                                                    const float* __restrict__ scales,
                                                    unsigned int* __restrict__ W8)
{
    const int idx = blockIdx.x * 256 + threadIdx.x;   // 0..131071
    const int dir = idx >> 16;
    const int rem = idx & 65535;
    int slot, t, j, kw;
    if (rem < STAT_U32) {
        slot = rem >> 11; const int r2 = rem & 2047; t = r2 >> 2; j = r2 & 3;
        kw = 2 * slot + (j >> 1);
    } else {
        const int q2 = rem - STAT_U32;
        slot = q2 >> 11; const int r2 = q2 & 2047; t = r2 >> 2; j = r2 & 3;
        kw = 2 * NSTAT + 2 * slot + (j >> 1);
    }
    const int rr = j & 1;
    const int u  = t >> 1;                 // pair-lane mapping
    const int gs = (t & 1) * 2 + rr;
    const int row = gs * 256 + u;
    const float* W = dir ? Whh_b : Whh_f;
    const float sc = scales[dir * 1024 + row];
    const float inv = 1.f / sc;
    unsigned int v = 0;
    #pragma unroll
    for (int i = 0; i < 4; ++i) {
        const float w = W[(size_t)row * 256 + kw * 4 + i];
        int q = (int)rintf(w * inv);
        q = q > 127 ? 127 : (q < -127 ? -127 : q);
        v |= ((unsigned int)(unsigned char)(signed char)q) << (8 * i);
    }
    W8[idx] = v;
}

// ---------------------------------------------------------------------------
// wl8_kernel: quantize emission weights per (dir, tag). 1 block x 512 thr.
// ---------------------------------------------------------------------------
__global__ __launch_bounds__(512) void wl8_kernel(const float* __restrict__ Wlin,
                                                  unsigned int* __restrict__ wl8T,
                                                  float* __restrict__ scfac)
{
    const int w = threadIdx.x >> 6;      // 0..7
    const int lane = threadIdx.x & 63;
    const int dir = w >> 2, t = w & 3;
    const float4 v = *(const float4*)(Wlin + t * (2 * Hh) + dir * 256 + lane * 4);
    float m = fmaxf(fmaxf(fabsf(v.x), fabsf(v.y)), fmaxf(fabsf(v.z), fabsf(v.w)));
    #pragma unroll
    for (int off = 32; off > 0; off >>= 1) m = fmaxf(m, __shfl_down(m, off));
    const float mall = __builtin_amdgcn_readfirstlane(m);
    const float sc = fmaxf(mall, 1e-12f) / 127.f;
    const float inv = 1.f / sc;
    const float vv[4] = {v.x, v.y, v.z, v.w};
    unsigned int pk = 0;
    #pragma unroll
    for (int i = 0; i < 4; ++i) {
        int q = (int)rintf(vv[i] * inv);
        q = q > 127 ? 127 : (q < -127 ? -127 : q);
        pk |= ((unsigned int)(unsigned char)(signed char)q) << (8 * i);
    }
    wl8T[w * 64 + lane] = pk;
    if (lane == 0) scfac[w] = sc / 127.f;
}

// ---------------------------------------------------------------------------
// embproj GEMM: embproj[dir][v][j'] = sum_e emb[v][e]*WihP[dir][e][j'] + bP[dir][j']
// ---------------------------------------------------------------------------
#define BM 64
#define BN 128
#define BK 16
__global__ __launch_bounds__(256) void embproj_gemm(const float* __restrict__ emb,
                                                    const float* __restrict__ WihP,
                                                    const float* __restrict__ bP,
                                                    float* __restrict__ embproj)
{
    int dir = blockIdx.z;
    const float* Bmat = WihP + dir * WMAT_PER_DIR;
    float* C = embproj + (size_t)dir * EPROJ_PER_DIR;
    int m0 = blockIdx.x * BM;
    int n0 = blockIdx.y * BN;

    __shared__ float As[BK][BM];
    __shared__ float Bs[BK][BN];

    int t = threadIdx.x;
    int tm = (t & 15) * 4;
    int tn = (t >> 4) * 8;
    float acc[4][8];
    #pragma unroll
    for (int i = 0; i < 4; ++i)
        #pragma unroll
        for (int j = 0; j < 8; ++j) acc[i][j] = 0.f;

    for (int k0 = 0; k0 < Ee; k0 += BK) {
        {   // A tile 64x16
            int row = t >> 2, seg = t & 3;
            float4 a4 = *(const float4*)(&emb[(size_t)(m0 + row) * Ee + k0 + seg * 4]);
            As[seg * 4 + 0][row] = a4.x;
            As[seg * 4 + 1][row] = a4.y;
            As[seg * 4 + 2][row] = a4.z;
            As[seg * 4 + 3][row] = a4.w;
        }
        {   // B tile 16x128
            int kk = t >> 4, nn = (t & 15) * 8;
            float4 b0 = *(const float4*)(&Bmat[(size_t)(k0 + kk) * 1024 + n0 + nn]);
            float4 b1 = *(const float4*)(&Bmat[(size_t)(k0 + kk) * 1024 + n0 + nn + 4]);
            *(float4*)&Bs[kk][nn]     = b0;
            *(float4*)&Bs[kk][nn + 4] = b1;
        }
        __syncthreads();
        #pragma unroll
        for (int k = 0; k < BK; ++k) {
            float4 a  = *(const float4*)&As[k][tm];
            float4 b0 = *(const float4*)&Bs[k][tn];
            float4 b1 = *(const float4*)&Bs[k][tn + 4];
            float av[4] = {a.x, a.y, a.z, a.w};
            float bv[8] = {b0.x, b0.y, b0.z, b0.w, b1.x, b1.y, b1.z, b1.w};
            #pragma unroll
            for (int i = 0; i < 4; ++i)
                #pragma unroll
                for (int j = 0; j < 8; ++j)
                    acc[i][j] += av[i] * bv[j];
        }
        __syncthreads();
    }
    #pragma unroll
    for (int i = 0; i < 4; ++i) {
        int m = m0 + tm + i;
        #pragma unroll
        for (int j = 0; j < 8; j += 4) {
            float4 o;
            o.x = acc[i][j + 0] + bP[dir * 1024 + n0 + tn + j + 0];
            o.y = acc[i][j + 1] + bP[dir * 1024 + n0 + tn + j + 1];
            o.z = acc[i][j + 2] + bP[dir * 1024 + n0 + tn + j + 2];
            o.w = acc[i][j + 3] + bP[dir * 1024 + n0 + tn + j + 3];
            *(float4*)&C[(size_t)m * 1024 + n0 + tn + j] = o;
        }
    }
}

// ---------------------------------------------------------------------------
// R16 LSTM: R15 structure + (1) sb[] FORCE-PINNED in VGPRs via asm value
// barriers (R15 evidence: compiler sank the "hoisted" loads back into the
// loop -- VGPR stayed 88; 24 uint4 re-loaded from L2 every step was the
// exposed-latency wall). Cap waves_per_eu(2,2) -> 256 VGPR budget; need ~190.
// (2) ep (embproj token row) software-pipelined one step ahead -- the only
// remaining in-loop global load.
// ---------------------------------------------------------------------------
__global__ __attribute__((amdgpu_flat_work_group_size(512, 512)))
__attribute__((amdgpu_waves_per_eu(2, 2))) void lstm_stream_kernel(
    const int* __restrict__ sentence,
    const float* __restrict__ embproj,
    const unsigned int* __restrict__ W8,
    const float* __restrict__ scales,
    const unsigned int* __restrict__ wl8T,
    const float* __restrict__ scfac,
    float* __restrict__ emisP)
{
    extern __shared__ char smem[];
    uint4*        SWl = (uint4*)smem;                       // NSTAT*512 uint4 = 64KB
    unsigned int* h8  = (unsigned int*)(smem + STAT_U32*4); // [2][64] u32

    const int bx  = blockIdx.x;
    const int dir = bx >> 6;
    const int b   = bx & 63;
    const int t   = threadIdx.x;
    const int lane = t & 63, wv = t >> 6;
    const int u    = t >> 1;            // pair-lane unit
    const int gs0  = (t & 1) * 2;       // 0: rows i,f | 2: rows g,o
    const bool ev  = !(t & 1);

    const unsigned int* Wd   = W8 + (size_t)dir * 65536;
    const unsigned int* Wstr = Wd + STAT_U32;

    // stage static weight section into LDS (coalesced)
    #pragma unroll
    for (int i = 0; i < NSTAT; ++i)
        SWl[i * 512 + t] = *(const uint4*)(Wd + (size_t)(i * 512 + t) * 4);
    if (t < 128) h8[t] = 0u;   // h(-1) = 0, both parity slots

    // "streamed" slots -> registers, FORCE-pinned (asm makes the values
    // opaque: compiler cannot rematerialize the loads inside the loop)
    uint4 sb[NSTRM];
    #pragma unroll
    for (int i = 0; i < NSTRM; ++i)
        sb[i] = *(const uint4*)(Wstr + (size_t)(i * 512 + t) * 4);
    #pragma unroll
    for (int i = 0; i < NSTRM; ++i)
        asm volatile("" : "+v"(sb[i].x), "+v"(sb[i].y), "+v"(sb[i].z), "+v"(sb[i].w));

    const float sc0 = scales[dir * 1024 + (gs0 + 0) * 256 + u] * (1.f / 127.f);
    const float sc1 = scales[dir * 1024 + (gs0 + 1) * 256 + u] * (1.f / 127.f);
    const float* EP = embproj + (size_t)dir * EPROJ_PER_DIR;
    const int* sent = sentence + (size_t)b * Ss;
    float c = 0.f;

    // wave-4 emission state (registers)
    unsigned int wlq0 = 0, wlq1 = 0, wlq2 = 0, wlq3 = 0;
    float4 efac = make_float4(0.f, 0.f, 0.f, 0.f);
    if (wv == 4) {
        wlq0 = wl8T[(dir * 4 + 0) * 64 + lane];
        wlq1 = wl8T[(dir * 4 + 1) * 64 + lane];
        wlq2 = wl8T[(dir * 4 + 2) * 64 + lane];
        wlq3 = wl8T[(dir * 4 + 3) * 64 + lane];
        efac = *(const float4*)&scfac[dir * 4];
    }

    // ep software pipeline: preload step 0
    float2 ep_cur;
    {
        const int pos0 = dir ? (Ss - 1) : 0;
        ep_cur = *(const float2*)(EP + (size_t)sent[pos0] * 1024 + u * 4 + gs0);
    }

    __syncthreads();

    for (int s = 0; s < Ss; ++s) {
        const int pos = dir ? (Ss - 1 - s) : s;

        // issue next step's ep load early (covers L2/L3 latency with compute)
        float2 ep_nxt = make_float2(0.f, 0.f);
        if (s + 1 < Ss) {
            const int pn = dir ? (Ss - 2 - s) : (s + 1);
            ep_nxt = *(const float2*)(EP + (size_t)sent[pn] * 1024 + u * 4 + gs0);
        }

        const int rp = (s + 1) & 1;        // slot holding h(s-1)
        const int wp = s & 1;              // slot to write h(s)
        const int v_h = (int)h8[rp * 64 + lane];

        // emission of h(s-1) (wave 4 only): 4 sdot4 + int shfl reduce
        if (wv == 4 && s > 0) {
            int e0 = dot4i8(wlq0, (unsigned)v_h, 0);
            int e1 = dot4i8(wlq1, (unsigned)v_h, 0);
            int e2 = dot4i8(wlq2, (unsigned)v_h, 0);
            int e3 = dot4i8(wlq3, (unsigned)v_h, 0);
            #pragma unroll
            for (int off = 32; off > 0; off >>= 1) {
                e0 += __shfl_down(e0, off); e1 += __shfl_down(e1, off);
                e2 += __shfl_down(e2, off); e3 += __shfl_down(e3, off);
            }
            if (lane == 0) {
                const int pp = dir ? (Ss - s) : (s - 1);
                float4 o;
                o.x = (float)e0 * efac.x; o.y = (float)e1 * efac.y;
                o.z = (float)e2 * efac.z; o.w = (float)e3 * efac.w;
                *(float4*)&emisP[(((size_t)dir * Ss + pp) * Bb + b) * 4] = o;
            }
        }

        // gate dots: readlane h (uniform SGPR) x int8 weights; split chains
        int a0e = 0, a1e = 0, a0o = 0, a1o = 0;
        #pragma unroll
        for (int i = 0; i < NSTAT; ++i) {
            const uint4 w = SWl[i * 512 + t];
            const unsigned h0 = (unsigned)__builtin_amdgcn_readlane(v_h, 2 * i);
            const unsigned h1 = (unsigned)__builtin_amdgcn_readlane(v_h, 2 * i + 1);
            if (i & 1) {
                a0o = dot4i8(w.x, h0, a0o); a1o = dot4i8(w.y, h0, a1o);
                a0o = dot4i8(w.z, h1, a0o); a1o = dot4i8(w.w, h1, a1o);
            } else {
                a0e = dot4i8(w.x, h0, a0e); a1e = dot4i8(w.y, h0, a1e);
                a0e = dot4i8(w.z, h1, a0e); a1e = dot4i8(w.w, h1, a1e);
            }
        }
        #pragma unroll
        for (int i = 0; i < NSTRM; ++i) {
            const uint4 w = sb[i];
            const unsigned h0 = (unsigned)__builtin_amdgcn_readlane(v_h, 2 * NSTAT + 2 * i);
            const unsigned h1 = (unsigned)__builtin_amdgcn_readlane(v_h, 2 * NSTAT + 2 * i + 1);
            if (i & 1) {
                a0o = dot4i8(w.x, h0, a0o); a1o = dot4i8(w.y, h0, a1o);
                a0o = dot4i8(w.z, h1, a0o); a1o = dot4i8(w.w, h1, a1o);
            } else {
                a0e = dot4i8(w.x, h0, a0e); a1e = dot4i8(w.y, h0, a1e);
                a0e = dot4i8(w.z, h1, a0e); a1e = dot4i8(w.w, h1, a1e);
            }
        }
        const int a0 = a0e + a0o, a1 = a1e + a1o;

        const float g0 = (float)a0 * sc0 + ep_cur.x;   // ev: i  | odd: g
        const float g1 = (float)a1 * sc1 + ep_cur.y;   // ev: f  | odd: o
        // pair exchange: even lane gets (g,o) from odd partner
        const float pg0 = __shfl_xor(g0, 1);
        const float pg1 = __shfl_xor(g1, 1);
        if (ev) {
            c = sigm(g1) * c + sigm(g0) * tanhf(pg0);
            const float h = sigm(pg1) * tanhf(c);
            ((char*)h8)[wp * 256 + u] = (char)(int)rintf(h * 127.f);   // |h|<1
        }
        ep_cur = ep_nxt;
        __syncthreads();   // separates step-s h8 reads from step-s+1 writes
    }

    // epilogue: emission for h(Ss-1)
    if (wv == 4) {
        const int v_h = (int)h8[((Ss - 1) & 1) * 64 + lane];
        int e0 = dot4i8(wlq0, (unsigned)v_h, 0);
        int e1 = dot4i8(wlq1, (unsigned)v_h, 0);
        int e2 = dot4i8(wlq2, (unsigned)v_h, 0);
        int e3 = dot4i8(wlq3, (unsigned)v_h, 0);
        #pragma unroll
        for (int off = 32; off > 0; off >>= 1) {
            e0 += __shfl_down(e0, off); e1 += __shfl_down(e1, off);
            e2 += __shfl_down(e2, off); e3 += __shfl_down(e3, off);
        }
        if (lane == 0) {
            const int pp = dir ? 0 : (Ss - 1);
            float4 o;
            o.x = (float)e0 * efac.x; o.y = (float)e1 * efac.y;
            o.z = (float)e2 * efac.z; o.w = (float)e3 * efac.w;
            *(float4*)&emisP[(((size_t)dir * Ss + pp) * Bb + b) * 4] = o;
        }
    }
}

// ---------------------------------------------------------------------------
// Fused CRF + Viterbi tail. grid 8 x 64 threads. emis = emisP[0] + emisP[1].
// ---------------------------------------------------------------------------
#define EM2(S_, B_, J_) (emisA[(((size_t)(S_)) * Bb + (B_)) * 4 + (J_)] + \
                         emisB[(((size_t)(S_)) * Bb + (B_)) * 4 + (J_)])

__global__ __launch_bounds__(64) void tail_kernel(
    const float* __restrict__ emisA, const float* __restrict__ emisB,
    const float* __restrict__ blin, const float* __restrict__ start_t,
    const float* __restrict__ end_t, const float* __restrict__ trans,
    const int* __restrict__ tags, float* __restrict__ out_tags,
    float* __restrict__ out_loss)
{
    const int blk = blockIdx.x;
    const int t = threadIdx.x;
    const int b_loc = t >> 2, j = t & 3;
    const int base = t & ~3;

    if (blk < 4) {
        __shared__ unsigned char bp_sh[16][513][4];
        __shared__ unsigned char tag_sh[16][520];
        const int b = blk * 16 + b_loc;
        const float trj0 = trans[0*4+j], trj1 = trans[1*4+j],
                    trj2 = trans[2*4+j], trj3 = trans[3*4+j];
        const float blj = blin[j];
        float score = start_t[j] + EM2(0, b, j) + blj;
        for (int s = 1; s < Ss; ++s) {
            const float e = EM2(s, b, j) + blj;
            const float s0 = __shfl(score, base+0), s1 = __shfl(score, base+1),
                        s2 = __shfl(score, base+2), s3 = __shfl(score, base+3);
            float best = s0 + trj0; int bi = 0;
            float v = s1 + trj1; if (v > best) { best = v; bi = 1; }
            v = s2 + trj2; if (v > best) { best = v; bi = 2; }
            v = s3 + trj3; if (v > best) { best = v; bi = 3; }
            score = best + e;
            bp_sh[b_loc][s][j] = (unsigned char)bi;
        }
        const float fv = score + end_t[j];
        const float f0 = __shfl(fv, base+0), f1 = __shfl(fv, base+1),
                    f2 = __shfl(fv, base+2), f3 = __shfl(fv, base+3);
        __syncthreads();
        if (j == 0) {   // backtrack (first-occurrence argmax, like jnp)
            float best = f0; int tag = 0;
            if (f1 > best) { best = f1; tag = 1; }
            if (f2 > best) { best = f2; tag = 2; }
            if (f3 > best) { best = f3; tag = 3; }
            tag_sh[b_loc][Ss-1] = (unsigned char)tag;
            for (int s = Ss - 1; s >= 1; --s) {
                tag = bp_sh[b_loc][s][tag];
                tag_sh[b_loc][s-1] = (unsigned char)tag;
            }
        }
        __syncthreads();
        for (int idx = t; idx < 16 * Ss; idx += 64) {
            const int bl = idx >> 9, s = idx & (Ss - 1);
            out_tags[(size_t)(blk*16 + bl) * Ss + s] = (float)tag_sh[bl][s];
        }
    } else {
        const int b = (blk - 4) * 16 + b_loc;
        const float trj0 = trans[0*4+j], trj1 = trans[1*4+j],
                    trj2 = trans[2*4+j], trj3 = trans[3*4+j];
        const float blj = blin[j];
        float alpha = start_t[j] + EM2(0, b, j) + blj;
        for (int s = 1; s < Ss; ++s) {
            const float e = EM2(s, b, j) + blj;
            const float a0 = __shfl(alpha, base+0), a1 = __shfl(alpha, base+1),
                        a2 = __shfl(alpha, base+2), a3 = __shfl(alpha, base+3);
            const float x0 = a0 + trj0, x1 = a1 + trj1, x2 = a2 + trj2, x3 = a3 + trj3;
            const float m = fmaxf(fmaxf(x0, x1), fmaxf(x2, x3));
            alpha = m + logf(expf(x0-m) + expf(x1-m) + expf(x2-m) + expf(x3-m)) + e;
        }
        const float dv = alpha + end_t[j];
        const float d0 = __shfl(dv, base+0), d1 = __shfl(dv, base+1),
                    d2 = __shfl(dv, base+2), d3 = __shfl(dv, base+3);
        const float dm = fmaxf(fmaxf(d0, d1), fmaxf(d2, d3));
        const float denom = dm + logf(expf(d0-dm) + expf(d1-dm) + expf(d2-dm) + expf(d3-dm));

        const int lo = j * 128, hi = lo + 128;
        float num = 0.f;
        int tprev = (lo > 0) ? tags[(size_t)b*Ss + lo - 1] : 0;
        if (j == 0) num += start_t[tags[(size_t)b*Ss]];
        if (j == 3) num += end_t[tags[(size_t)b*Ss + Ss - 1]];
        for (int s = lo; s < hi; ++s) {
            const int tg = tags[(size_t)b*Ss + s];
            num += EM2(s, b, tg) + blin[tg];
            if (s > 0) num += trans[tprev*4 + tg];
            tprev = tg;
        }
        num += __shfl_xor(num, 1);
        num += __shfl_xor(num, 2);
        float lb = (j == 0) ? (denom - num) : 0.f;
        #pragma unroll
        for (int off = 32; off > 0; off >>= 1) lb += __shfl_down(lb, off);
        if (t == 0) atomicAdd(out_loss, lb);
    }
}

// ---------------------------------------------------------------------------
extern "C" void kernel_launch(void* const* d_in, const int* in_sizes, int n_in,
                              void* d_out, int out_size, void* d_ws, size_t ws_size,
                              hipStream_t stream)
{
    const int*   sentence = (const int*)d_in[0];
    const int*   tags     = (const int*)d_in[1];
    const float* emb      = (const float*)d_in[3];
    const float* Wih_f    = (const float*)d_in[4];
    const float* Whh_f    = (const float*)d_in[5];
    const float* b_f      = (const float*)d_in[6];
    const float* Wih_b    = (const float*)d_in[7];
    const float* Whh_b    = (const float*)d_in[8];
    const float* b_b      = (const float*)d_in[9];
    const float* Wlin     = (const float*)d_in[10];
    const float* blin     = (const float*)d_in[11];
    const float* start_t  = (const float*)d_in[12];
    const float* end_t    = (const float*)d_in[13];
    const float* trans    = (const float*)d_in[14];

    // workspace layout (floats)
    float*        embproj = (float*)d_ws;                      // 16,384,000
    float*        WihP    = embproj + 2 * EPROJ_PER_DIR;       // 524,288
    float*        bP      = WihP + 2 * WMAT_PER_DIR;           // 2048
    float*        WlinQ   = bP + 2048;                         // 2048
    float*        scales  = WlinQ + 2048;                      // 2048
    unsigned int* W8      = (unsigned int*)(scales + 2048);    // 131,072 u32
    unsigned int* wl8T    = W8 + 131072;                       // 512 u32
    float*        scfac   = (float*)(wl8T + 512);              // 8
    float*        emisP   = scfac + 56;                        // 2*512*64*4 (16B aligned)
    float*        emisA   = emisP;
    float*        emisB   = emisP + Ss * Bb * 4;

    prep1_kernel<<<2048, 256, 0, stream>>>(Wih_f, b_f, Wih_b, b_b, Wlin,
                                           WihP, bP, WlinQ);
    scale_kernel<<<512, 256, 0, stream>>>(Whh_f, Whh_b, scales);
    quant_kernel<<<512, 256, 0, stream>>>(Whh_f, Whh_b, scales, W8);
    wl8_kernel<<<1, 512, 0, stream>>>(Wlin, wl8T, scfac);

    dim3 gg(Vv / BM, 1024 / BN, 2);
    embproj_gemm<<<gg, 256, 0, stream>>>(emb, WihP, bP, embproj);

    lstm_stream_kernel<<<128, 512, STAT_U32 * 4 + 512, stream>>>(
        sentence, embproj, W8, scales, wl8T, scfac, emisP);

    float* out = (float*)d_out;
    float* out_loss = out + Bb * Ss;
    hipMemsetAsync(out_loss, 0, sizeof(float), stream);
    tail_kernel<<<8, 64, 0, stream>>>(emisA, emisB, blin, start_t, end_t, trans,
                                      tags, out, out_loss);
}

// Round 17
// 902.516 us; speedup vs baseline: 2.3118x; 1.1734x over previous
//
#include <hip/hip_runtime.h>
#include <math.h>

// Problem constants
#define Vv 8000
#define Ee 256
#define Hh 256
#define Tt 4
#define Bb 64
#define Ss 512

#define EPROJ_PER_DIR (Vv * 1024)   // 8,192,000 floats per direction
#define WMAT_PER_DIR  (Ee * 1024)   // 262,144 floats per direction

// int8 weight image geometry (per dir = 65536 u32 = 256KB):
//   64 k-words (kw) of 4 k each. LDS-static kw 0..2*NSTAT-1, L2-streamed
//   kw 2*NSTAT..63. u32 at (sec, slot, t, j):
//     kw = (sec? 2*NSTAT:0) + 2*slot + (j>>1), rr = j&1
//     PAIR-LANE mapping: u = t>>1, gs = (t&1)*2 + rr
//     row_orig = gs*256 + u   [gate-major, as input Whh]
//   Thread t consumes uint4 (slot*512+t) -> lane-linear, coalesced/conflict-free.
#define NSTAT 8
#define NSTRM 24
#define STAT_U32 (NSTAT * 512 * 4)   // 16384

#if defined(__has_builtin)
# if __has_builtin(__builtin_amdgcn_sdot4)
#  define HAS_SDOT4 1
# endif
# if __has_builtin(__builtin_amdgcn_exp2f) && __has_builtin(__builtin_amdgcn_rcpf)
#  define HAS_FASTTRANS 1
# endif
#endif

__device__ __forceinline__ float sigm(float x) { return 1.f / (1.f + expf(-x)); }

// fast sigmoid/tanh on v_exp_f32 + v_rcp_f32 (saturate correctly at +-inf;
// ~1e-6 rel err, far below the int8 quantization noise already present)
__device__ __forceinline__ float sigm_f(float x) {
#ifdef HAS_FASTTRANS
    const float e = __builtin_amdgcn_exp2f(-1.44269504f * x);
    return __builtin_amdgcn_rcpf(1.f + e);
#else
    return 1.f / (1.f + expf(-x));
#endif
}
__device__ __forceinline__ float tanh_f(float x) {
#ifdef HAS_FASTTRANS
    const float e = __builtin_amdgcn_exp2f(-2.88539008f * x);
    return 2.f * __builtin_amdgcn_rcpf(1.f + e) - 1.f;
#else
    return tanhf(x);
#endif
}

__device__ __forceinline__ int dot4i8(unsigned a, unsigned b, int c) {
#ifdef HAS_SDOT4
    return __builtin_amdgcn_sdot4((int)a, (int)b, c, false);
#else
    int s = c;
    #pragma unroll
    for (int i = 0; i < 4; ++i) {
        const int xa = ((int)(a << (24 - 8 * i))) >> 24;
        const int xb = ((int)(b << (24 - 8 * i))) >> 24;
        s += xa * xb;
    }
    return s;
#endif
}

// ---------------------------------------------------------------------------
// prep1: WihP (GEMM B-matrix, j' = u*4+g <-> gate-row g*256+u), bP, WlinQ.
// ---------------------------------------------------------------------------
__global__ void prep1_kernel(const float* __restrict__ Wih_f, const float* __restrict__ b_f,
                             const float* __restrict__ Wih_b, const float* __restrict__ b_b,
                             const float* __restrict__ Wlin,
                             float* __restrict__ WihP, float* __restrict__ bP,
                             float* __restrict__ WlinQ)
{
    int tid = blockIdx.x * blockDim.x + threadIdx.x;   // [0, 2*262144)
    int dir = tid >> 18;
    int r   = tid & 262143;
    int k   = r >> 10;        // 0..255
    int jp  = r & 1023;       // j'
    int u   = jp >> 2;
    int g   = jp & 3;
    int row = g * 256 + u;
    const float* Wih = dir ? Wih_b : Wih_f;
    const float* bv  = dir ? b_b   : b_f;
    WihP[dir * WMAT_PER_DIR + k * 1024 + jp] = Wih[row * 256 + k];
    if (r < 1024) {
        bP[dir * 1024 + jp] = bv[row];
        int uu = r >> 2, tt = r & 3;
        WlinQ[(dir * 256 + uu) * 4 + tt] = Wlin[tt * (2 * Hh) + dir * 256 + uu];
    }
}

// ---------------------------------------------------------------------------
// scale_kernel: per gate-row absmax/127. 512 blocks x 256 thr; wave = one row.
// ---------------------------------------------------------------------------
__global__ __launch_bounds__(256) void scale_kernel(const float* __restrict__ Whh_f,
                                                    const float* __restrict__ Whh_b,
                                                    float* __restrict__ scales)
{
    const int gw = blockIdx.x * 4 + (threadIdx.x >> 6);   // 0..2047
    const int lane = threadIdx.x & 63;
    const int dir = gw >> 10;
    const int row = gw & 1023;
    const float* W = dir ? Whh_b : Whh_f;
    const float* src = W + (size_t)row * 256 + lane * 4;
    float m = fmaxf(fmaxf(fabsf(src[0]), fabsf(src[1])),
                    fmaxf(fabsf(src[2]), fabsf(src[3])));
    #pragma unroll
    for (int off = 32; off > 0; off >>= 1) m = fmaxf(m, __shfl_down(m, off));
    if (lane == 0) scales[gw] = fmaxf(m, 1e-12f) / 127.f;
}

// ---------------------------------------------------------------------------
// quant_kernel: build the permuted int8 image W8 (pair-lane mapping).
// ---------------------------------------------------------------------------
__global__ __launch_bounds__(256) void quant_kernel(const float* __restrict__ Whh_f,
                                                    const float* __restrict__ Whh_b,
                                                    const float* __restrict__ scales,
                                                    unsigned int* __restrict__ W8)
{
    const int idx = blockIdx.x * 256 + threadIdx.x;   // 0..131071
    const int dir = idx >> 16;
    const int rem = idx & 65535;
    int slot, t, j, kw;
    if (rem < STAT_U32) {
        slot = rem >> 11; const int r2 = rem & 2047; t = r2 >> 2; j = r2 & 3;
        kw = 2 * slot + (j >> 1);
    } else {
        const int q2 = rem - STAT_U32;
        slot = q2 >> 11; const int r2 = q2 & 2047; t = r2 >> 2; j = r2 & 3;
        kw = 2 * NSTAT + 2 * slot + (j >> 1);
    }
    const int rr = j & 1;
    const int u  = t >> 1;                 // pair-lane mapping
    const int gs = (t & 1) * 2 + rr;
    const int row = gs * 256 + u;
    const float* W = dir ? Whh_b : Whh_f;
    const float sc = scales[dir * 1024 + row];
    const float inv = 1.f / sc;
    unsigned int v = 0;
    #pragma unroll
    for (int i = 0; i < 4; ++i) {
        const float w = W[(size_t)row * 256 + kw * 4 + i];
        int q = (int)rintf(w * inv);
        q = q > 127 ? 127 : (q < -127 ? -127 : q);
        v |= ((unsigned int)(unsigned char)(signed char)q) << (8 * i);
    }
    W8[idx] = v;
}

// ---------------------------------------------------------------------------
// wl8_kernel: quantize emission weights per (dir, tag). 1 block x 512 thr.
// ---------------------------------------------------------------------------
__global__ __launch_bounds__(512) void wl8_kernel(const float* __restrict__ Wlin,
                                                  unsigned int* __restrict__ wl8T,
                                                  float* __restrict__ scfac)
{
    const int w = threadIdx.x >> 6;      // 0..7
    const int lane = threadIdx.x & 63;
    const int dir = w >> 2, t = w & 3;
    const float4 v = *(const float4*)(Wlin + t * (2 * Hh) + dir * 256 + lane * 4);
    float m = fmaxf(fmaxf(fabsf(v.x), fabsf(v.y)), fmaxf(fabsf(v.z), fabsf(v.w)));
    #pragma unroll
    for (int off = 32; off > 0; off >>= 1) m = fmaxf(m, __shfl_down(m, off));
    const float mall = __builtin_amdgcn_readfirstlane(m);
    const float sc = fmaxf(mall, 1e-12f) / 127.f;
    const float inv = 1.f / sc;
    const float vv[4] = {v.x, v.y, v.z, v.w};
    unsigned int pk = 0;
    #pragma unroll
    for (int i = 0; i < 4; ++i) {
        int q = (int)rintf(vv[i] * inv);
        q = q > 127 ? 127 : (q < -127 ? -127 : q);
        pk |= ((unsigned int)(unsigned char)(signed char)q) << (8 * i);
    }
    wl8T[w * 64 + lane] = pk;
    if (lane == 0) scfac[w] = sc / 127.f;
}

// ---------------------------------------------------------------------------
// embproj GEMM: embproj[dir][v][j'] = sum_e emb[v][e]*WihP[dir][e][j'] + bP[dir][j']
// ---------------------------------------------------------------------------
#define BM 64
#define BN 128
#define BK 16
__global__ __launch_bounds__(256) void embproj_gemm(const float* __restrict__ emb,
                                                    const float* __restrict__ WihP,
                                                    const float* __restrict__ bP,
                                                    float* __restrict__ embproj)
{
    int dir = blockIdx.z;
    const float* Bmat = WihP + dir * WMAT_PER_DIR;
    float* C = embproj + (size_t)dir * EPROJ_PER_DIR;
    int m0 = blockIdx.x * BM;
    int n0 = blockIdx.y * BN;

    __shared__ float As[BK][BM];
    __shared__ float Bs[BK][BN];

    int t = threadIdx.x;
    int tm = (t & 15) * 4;
    int tn = (t >> 4) * 8;
    float acc[4][8];
    #pragma unroll
    for (int i = 0; i < 4; ++i)
        #pragma unroll
        for (int j = 0; j < 8; ++j) acc[i][j] = 0.f;

    for (int k0 = 0; k0 < Ee; k0 += BK) {
        {   // A tile 64x16
            int row = t >> 2, seg = t & 3;
            float4 a4 = *(const float4*)(&emb[(size_t)(m0 + row) * Ee + k0 + seg * 4]);
            As[seg * 4 + 0][row] = a4.x;
            As[seg * 4 + 1][row] = a4.y;
            As[seg * 4 + 2][row] = a4.z;
            As[seg * 4 + 3][row] = a4.w;
        }
        {   // B tile 16x128
            int kk = t >> 4, nn = (t & 15) * 8;
            float4 b0 = *(const float4*)(&Bmat[(size_t)(k0 + kk) * 1024 + n0 + nn]);
            float4 b1 = *(const float4*)(&Bmat[(size_t)(k0 + kk) * 1024 + n0 + nn + 4]);
            *(float4*)&Bs[kk][nn]     = b0;
            *(float4*)&Bs[kk][nn + 4] = b1;
        }
        __syncthreads();
        #pragma unroll
        for (int k = 0; k < BK; ++k) {
            float4 a  = *(const float4*)&As[k][tm];
            float4 b0 = *(const float4*)&Bs[k][tn];
            float4 b1 = *(const float4*)&Bs[k][tn + 4];
            float av[4] = {a.x, a.y, a.z, a.w};
            float bv[8] = {b0.x, b0.y, b0.z, b0.w, b1.x, b1.y, b1.z, b1.w};
            #pragma unroll
            for (int i = 0; i < 4; ++i)
                #pragma unroll
                for (int j = 0; j < 8; ++j)
                    acc[i][j] += av[i] * bv[j];
        }
        __syncthreads();
    }
    #pragma unroll
    for (int i = 0; i < 4; ++i) {
        int m = m0 + tm + i;
        #pragma unroll
        for (int j = 0; j < 8; j += 4) {
            float4 o;
            o.x = acc[i][j + 0] + bP[dir * 1024 + n0 + tn + j + 0];
            o.y = acc[i][j + 1] + bP[dir * 1024 + n0 + tn + j + 1];
            o.z = acc[i][j + 2] + bP[dir * 1024 + n0 + tn + j + 2];
            o.w = acc[i][j + 3] + bP[dir * 1024 + n0 + tn + j + 3];
            *(float4*)&C[(size_t)m * 1024 + n0 + tn + j] = o;
        }
    }
}

// ---------------------------------------------------------------------------
// R17 LSTM: R16 structure with the step-critical-path shortened:
//  (1) activations on v_exp_f32/v_rcp_f32 (libm expf/tanhf chain was ~300-600
//      serial cycles on the h-publish path, invariant across R13-R16),
//  (2) 4 accumulator chains per gate output (sdot4 dep depth 32 -> 16),
//  (3) emission spread over waves 4-7, one tag each (removes the per-step
//      straggler wave the barrier waits on).
// ---------------------------------------------------------------------------
__global__ __attribute__((amdgpu_flat_work_group_size(512, 512)))
__attribute__((amdgpu_waves_per_eu(2, 2))) void lstm_stream_kernel(
    const int* __restrict__ sentence,
    const float* __restrict__ embproj,
    const unsigned int* __restrict__ W8,
    const float* __restrict__ scales,
    const unsigned int* __restrict__ wl8T,
    const float* __restrict__ scfac,
    float* __restrict__ emisP)
{
    extern __shared__ char smem[];
    uint4*        SWl = (uint4*)smem;                       // NSTAT*512 uint4 = 64KB
    unsigned int* h8  = (unsigned int*)(smem + STAT_U32*4); // [2][64] u32

    const int bx  = blockIdx.x;
    const int dir = bx >> 6;
    const int b   = bx & 63;
    const int t   = threadIdx.x;
    const int lane = t & 63, wv = t >> 6;
    const int u    = t >> 1;            // pair-lane unit
    const int gs0  = (t & 1) * 2;       // 0: rows i,f | 2: rows g,o
    const bool ev  = !(t & 1);

    const unsigned int* Wd   = W8 + (size_t)dir * 65536;
    const unsigned int* Wstr = Wd + STAT_U32;

    // stage static weight section into LDS (coalesced)
    #pragma unroll
    for (int i = 0; i < NSTAT; ++i)
        SWl[i * 512 + t] = *(const uint4*)(Wd + (size_t)(i * 512 + t) * 4);
    if (t < 128) h8[t] = 0u;   // h(-1) = 0, both parity slots

    const float sc0 = scales[dir * 1024 + (gs0 + 0) * 256 + u] * (1.f / 127.f);
    const float sc1 = scales[dir * 1024 + (gs0 + 1) * 256 + u] * (1.f / 127.f);
    const float* EP = embproj + (size_t)dir * EPROJ_PER_DIR;
    const int* sent = sentence + (size_t)b * Ss;
    float c = 0.f;

    // emission state: waves 4..7, one tag each
    unsigned int wlq = 0;
    float efac = 0.f;
    const int etag = wv - 4;
    if (wv >= 4) {
        wlq  = wl8T[(dir * 4 + etag) * 64 + lane];
        efac = scfac[dir * 4 + etag];
    }

    // ep software pipeline: preload step 0
    float2 ep_cur;
    {
        const int pos0 = dir ? (Ss - 1) : 0;
        ep_cur = *(const float2*)(EP + (size_t)sent[pos0] * 1024 + u * 4 + gs0);
    }

    __syncthreads();

    for (int s = 0; s < Ss; ++s) {
        // issue next step's ep load early
        float2 ep_nxt = make_float2(0.f, 0.f);
        if (s + 1 < Ss) {
            const int pn = dir ? (Ss - 2 - s) : (s + 1);
            ep_nxt = *(const float2*)(EP + (size_t)sent[pn] * 1024 + u * 4 + gs0);
        }

        const int rp = (s + 1) & 1;        // slot holding h(s-1)
        const int wp = s & 1;              // slot to write h(s)
        const int v_h = (int)h8[rp * 64 + lane];

        // streamed weight slots (L2-resident; compiler re-loads per step)
        uint4 sb[NSTRM];
        #pragma unroll
        for (int i = 0; i < NSTRM; ++i)
            sb[i] = *(const uint4*)(Wstr + (size_t)(i * 512 + t) * 4);

        // emission of h(s-1): waves 4-7, one tag each (1 sdot4 + reduce)
        if (wv >= 4 && s > 0) {
            int e = dot4i8(wlq, (unsigned)v_h, 0);
            #pragma unroll
            for (int off = 32; off > 0; off >>= 1) e += __shfl_down(e, off);
            if (lane == 0) {
                const int pp = dir ? (Ss - s) : (s - 1);
                emisP[(((size_t)dir * Ss + pp) * Bb + b) * 4 + etag] = (float)e * efac;
            }
        }

        // gate dots: readlane h (uniform SGPR) x int8 weights; 4 chains/output
        int a0c[4] = {0, 0, 0, 0};
        int a1c[4] = {0, 0, 0, 0};
        #pragma unroll
        for (int i = 0; i < NSTAT; ++i) {
            const uint4 w = SWl[i * 512 + t];
            const unsigned h0 = (unsigned)__builtin_amdgcn_readlane(v_h, 2 * i);
            const unsigned h1 = (unsigned)__builtin_amdgcn_readlane(v_h, 2 * i + 1);
            const int q = i & 3;
            a0c[q] = dot4i8(w.x, h0, a0c[q]); a1c[q] = dot4i8(w.y, h0, a1c[q]);
            a0c[q] = dot4i8(w.z, h1, a0c[q]); a1c[q] = dot4i8(w.w, h1, a1c[q]);
        }
        #pragma unroll
        for (int i = 0; i < NSTRM; ++i) {
            const uint4 w = sb[i];
            const unsigned h0 = (unsigned)__builtin_amdgcn_readlane(v_h, 2 * NSTAT + 2 * i);
            const unsigned h1 = (unsigned)__builtin_amdgcn_readlane(v_h, 2 * NSTAT + 2 * i + 1);
            const int q = i & 3;
            a0c[q] = dot4i8(w.x, h0, a0c[q]); a1c[q] = dot4i8(w.y, h0, a1c[q]);
            a0c[q] = dot4i8(w.z, h1, a0c[q]); a1c[q] = dot4i8(w.w, h1, a1c[q]);
        }
        const int a0 = (a0c[0] + a0c[1]) + (a0c[2] + a0c[3]);
        const int a1 = (a1c[0] + a1c[1]) + (a1c[2] + a1c[3]);

        const float g0 = (float)a0 * sc0 + ep_cur.x;   // ev: i  | odd: g
        const float g1 = (float)a1 * sc1 + ep_cur.y;   // ev: f  | odd: o
        // pair exchange: even lane gets (g,o) from odd partner
        const float pg0 = __shfl_xor(g0, 1);
        const float pg1 = __shfl_xor(g1, 1);
        if (ev) {
            c = sigm_f(g1) * c + sigm_f(g0) * tanh_f(pg0);
            const float h = sigm_f(pg1) * tanh_f(c);
            ((char*)h8)[wp * 256 + u] = (char)(int)rintf(h * 127.f);   // |h|<1
        }
        ep_cur = ep_nxt;
        __syncthreads();   // separates step-s h8 reads from step-s+1 writes
    }

    // epilogue: emission for h(Ss-1)
    if (wv >= 4) {
        const int v_h = (int)h8[((Ss - 1) & 1) * 64 + lane];
        int e = dot4i8(wlq, (unsigned)v_h, 0);
        #pragma unroll
        for (int off = 32; off > 0; off >>= 1) e += __shfl_down(e, off);
        if (lane == 0) {
            const int pp = dir ? 0 : (Ss - 1);
            emisP[(((size_t)dir * Ss + pp) * Bb + b) * 4 + etag] = (float)e * efac;
        }
    }
}

// ---------------------------------------------------------------------------
// Fused CRF + Viterbi tail. grid 8 x 64 threads. emis = emisP[0] + emisP[1].
// ---------------------------------------------------------------------------
#define EM2(S_, B_, J_) (emisA[(((size_t)(S_)) * Bb + (B_)) * 4 + (J_)] + \
                         emisB[(((size_t)(S_)) * Bb + (B_)) * 4 + (J_)])

__global__ __launch_bounds__(64) void tail_kernel(
    const float* __restrict__ emisA, const float* __restrict__ emisB,
    const float* __restrict__ blin, const float* __restrict__ start_t,
    const float* __restrict__ end_t, const float* __restrict__ trans,
    const int* __restrict__ tags, float* __restrict__ out_tags,
    float* __restrict__ out_loss)
{
    const int blk = blockIdx.x;
    const int t = threadIdx.x;
    const int b_loc = t >> 2, j = t & 3;
    const int base = t & ~3;

    if (blk < 4) {
        __shared__ unsigned char bp_sh[16][513][4];
        __shared__ unsigned char tag_sh[16][520];
        const int b = blk * 16 + b_loc;
        const float trj0 = trans[0*4+j], trj1 = trans[1*4+j],
                    trj2 = trans[2*4+j], trj3 = trans[3*4+j];
        const float blj = blin[j];
        float score = start_t[j] + EM2(0, b, j) + blj;
        for (int s = 1; s < Ss; ++s) {
            const float e = EM2(s, b, j) + blj;
            const float s0 = __shfl(score, base+0), s1 = __shfl(score, base+1),
                        s2 = __shfl(score, base+2), s3 = __shfl(score, base+3);
            float best = s0 + trj0; int bi = 0;
            float v = s1 + trj1; if (v > best) { best = v; bi = 1; }
            v = s2 + trj2; if (v > best) { best = v; bi = 2; }
            v = s3 + trj3; if (v > best) { best = v; bi = 3; }
            score = best + e;
            bp_sh[b_loc][s][j] = (unsigned char)bi;
        }
        const float fv = score + end_t[j];
        const float f0 = __shfl(fv, base+0), f1 = __shfl(fv, base+1),
                    f2 = __shfl(fv, base+2), f3 = __shfl(fv, base+3);
        __syncthreads();
        if (j == 0) {   // backtrack (first-occurrence argmax, like jnp)
            float best = f0; int tag = 0;
            if (f1 > best) { best = f1; tag = 1; }
            if (f2 > best) { best = f2; tag = 2; }
            if (f3 > best) { best = f3; tag = 3; }
            tag_sh[b_loc][Ss-1] = (unsigned char)tag;
            for (int s = Ss - 1; s >= 1; --s) {
                tag = bp_sh[b_loc][s][tag];
                tag_sh[b_loc][s-1] = (unsigned char)tag;
            }
        }
        __syncthreads();
        for (int idx = t; idx < 16 * Ss; idx += 64) {
            const int bl = idx >> 9, s = idx & (Ss - 1);
            out_tags[(size_t)(blk*16 + bl) * Ss + s] = (float)tag_sh[bl][s];
        }
    } else {
        const int b = (blk - 4) * 16 + b_loc;
        const float trj0 = trans[0*4+j], trj1 = trans[1*4+j],
                    trj2 = trans[2*4+j], trj3 = trans[3*4+j];
        const float blj = blin[j];
        float alpha = start_t[j] + EM2(0, b, j) + blj;
        for (int s = 1; s < Ss; ++s) {
            const float e = EM2(s, b, j) + blj;
            const float a0 = __shfl(alpha, base+0), a1 = __shfl(alpha, base+1),
                        a2 = __shfl(alpha, base+2), a3 = __shfl(alpha, base+3);
            const float x0 = a0 + trj0, x1 = a1 + trj1, x2 = a2 + trj2, x3 = a3 + trj3;
            const float m = fmaxf(fmaxf(x0, x1), fmaxf(x2, x3));
            alpha = m + logf(expf(x0-m) + expf(x1-m) + expf(x2-m) + expf(x3-m)) + e;
        }
        const float dv = alpha + end_t[j];
        const float d0 = __shfl(dv, base+0), d1 = __shfl(dv, base+1),
                    d2 = __shfl(dv, base+2), d3 = __shfl(dv, base+3);
        const float dm = fmaxf(fmaxf(d0, d1), fmaxf(d2, d3));
        const float denom = dm + logf(expf(d0-dm) + expf(d1-dm) + expf(d2-dm) + expf(d3-dm));

        const int lo = j * 128, hi = lo + 128;
        float num = 0.f;
        int tprev = (lo > 0) ? tags[(size_t)b*Ss + lo - 1] : 0;
        if (j == 0) num += start_t[tags[(size_t)b*Ss]];
        if (j == 3) num += end_t[tags[(size_t)b*Ss + Ss - 1]];
        for (int s = lo; s < hi; ++s) {
            const int tg = tags[(size_t)b*Ss + s];
            num += EM2(s, b, tg) + blin[tg];
            if (s > 0) num += trans[tprev*4 + tg];
            tprev = tg;
        }
        num += __shfl_xor(num, 1);
        num += __shfl_xor(num, 2);
        float lb = (j == 0) ? (denom - num) : 0.f;
        #pragma unroll
        for (int off = 32; off > 0; off >>= 1) lb += __shfl_down(lb, off);
        if (t == 0) atomicAdd(out_loss, lb);
    }
}

// ---------------------------------------------------------------------------
extern "C" void kernel_launch(void* const* d_in, const int* in_sizes, int n_in,
                              void* d_out, int out_size, void* d_ws, size_t ws_size,
                              hipStream_t stream)
{
    const int*   sentence = (const int*)d_in[0];
    const int*   tags     = (const int*)d_in[1];
    const float* emb      = (const float*)d_in[3];
    const float* Wih_f    = (const float*)d_in[4];
    const float* Whh_f    = (const float*)d_in[5];
    const float* b_f      = (const float*)d_in[6];
    const float* Wih_b    = (const float*)d_in[7];
    const float* Whh_b    = (const float*)d_in[8];
    const float* b_b      = (const float*)d_in[9];
    const float* Wlin     = (const float*)d_in[10];
    const float* blin     = (const float*)d_in[11];
    const float* start_t  = (const float*)d_in[12];
    const float* end_t    = (const float*)d_in[13];
    const float* trans    = (const float*)d_in[14];

    // workspace layout (floats)
    float*        embproj = (float*)d_ws;                      // 16,384,000
    float*        WihP    = embproj + 2 * EPROJ_PER_DIR;       // 524,288
    float*        bP      = WihP + 2 * WMAT_PER_DIR;           // 2048
    float*        WlinQ   = bP + 2048;                         // 2048
    float*        scales  = WlinQ + 2048;                      // 2048
    unsigned int* W8      = (unsigned int*)(scales + 2048);    // 131,072 u32
    unsigned int* wl8T    = W8 + 131072;                       // 512 u32
    float*        scfac   = (float*)(wl8T + 512);              // 8
    float*        emisP   = scfac + 56;                        // 2*512*64*4 (16B aligned)
    float*        emisA   = emisP;
    float*        emisB   = emisP + Ss * Bb * 4;

    prep1_kernel<<<2048, 256, 0, stream>>>(Wih_f, b_f, Wih_b, b_b, Wlin,
                                           WihP, bP, WlinQ);
    scale_kernel<<<512, 256, 0, stream>>>(Whh_f, Whh_b, scales);
    quant_kernel<<<512, 256, 0, stream>>>(Whh_f, Whh_b, scales, W8);
    wl8_kernel<<<1, 512, 0, stream>>>(Wlin, wl8T, scfac);

    dim3 gg(Vv / BM, 1024 / BN, 2);
    embproj_gemm<<<gg, 256, 0, stream>>>(emb, WihP, bP, embproj);

    lstm_stream_kernel<<<128, 512, STAT_U32 * 4 + 512, stream>>>(
        sentence, embproj, W8, scales, wl8T, scfac, emisP);

    float* out = (float*)d_out;
    float* out_loss = out + Bb * Ss;
    hipMemsetAsync(out_loss, 0, sizeof(float), stream);
    tail_kernel<<<8, 64, 0, stream>>>(emisA, emisB, blin, start_t, end_t, trans,
                                      tags, out, out_loss);
}